// Round 3
// baseline (396.857 us; speedup 1.0000x reference)
//
#include <hip/hip_runtime.h>

typedef unsigned short u16;
typedef unsigned int u32;
typedef float f32x4 __attribute__((ext_vector_type(4)));
typedef __bf16 bf16x8 __attribute__((ext_vector_type(8)));
typedef __bf16 bf16x4 __attribute__((ext_vector_type(4)));

#define LAMBDA_INIT_F 0.7836057665316245f
#define ONE_MINUS_LI  0.2163942334683755f
#define THR_LOG2 11.0f
// 0.125 * log2(e): fold softmax base-2 conversion into Q scaling
#define Q_SCALE 0.18033688011112042f

__device__ __forceinline__ u16 f2b(float f) {
  union { float f; u32 u; } x; x.f = f;
  u32 r = x.u + 0x7fffu + ((x.u >> 16) & 1u);
  return (u16)(r >> 16);
}

__device__ __forceinline__ f32x4 mfma16(bf16x8 a, bf16x8 b, f32x4 c) {
  return __builtin_amdgcn_mfma_f32_16x16x32_bf16(a, b, c, 0, 0, 0);
}

// async global->LDS, 16B per lane; LDS dest must be linear in lane order
__device__ __forceinline__ void gll16(const void* gp, void* lp) {
  __builtin_amdgcn_global_load_lds((__attribute__((address_space(1))) void*)(gp),
                                   (__attribute__((address_space(3))) void*)(lp),
                                   16, 0, 0);
}

// ---------------- fused cast f32 -> bf16 for q,k,v (8 elems/thread) -----------
__global__ __launch_bounds__(256) void cast3_kernel(const float* __restrict__ q,
                                                    const float* __restrict__ k,
                                                    const float* __restrict__ v,
                                                    u16* __restrict__ qb,
                                                    u16* __restrict__ kb,
                                                    u16* __restrict__ vb) {
  int bid = blockIdx.x;
  int seg = bid >> 11;
  int i = (bid & 2047) * 256 + threadIdx.x;
  const float* in = seg == 0 ? q : (seg == 1 ? k : v);
  u16* out = seg == 0 ? qb : (seg == 1 ? kb : vb);
  const f32x4* p = (const f32x4*)(in + (size_t)i * 8);
  f32x4 a = p[0], b = p[1];
  union { u16 u[8]; f32x4 v; } o;
#pragma unroll
  for (int j = 0; j < 4; ++j) { o.u[j] = f2b(a[j]); o.u[4 + j] = f2b(b[j]); }
  *(f32x4*)(out + (size_t)i * 8) = o.v;
}

// ------------- tiled transpose+cast: in f32 [R][C] -> out bf16 [C][R] ---------
__device__ __forceinline__ void trans_body(const float* __restrict__ in,
                                           u16* __restrict__ out, int R, int C) {
  __shared__ float tile[32][33];
  int bx = blockIdx.x * 32;  // col base
  int by = blockIdx.y * 32;  // row base
  int tx = threadIdx.x & 31, ty = threadIdx.x >> 5;
#pragma unroll
  for (int i = 0; i < 32; i += 8)
    tile[ty + i][tx] = in[(size_t)(by + ty + i) * C + bx + tx];
  __syncthreads();
#pragma unroll
  for (int i = 0; i < 32; i += 8)
    out[(size_t)(bx + ty + i) * R + by + tx] = f2b(tile[tx][ty + i]);
}

__global__ __launch_bounds__(256) void transpose_cast_kernel(const float* __restrict__ in,
                                                             u16* __restrict__ out,
                                                             int R, int C) {
  trans_body(in, out, R, C);
}

// all 4 weight transposes in one launch (grid.z selects)
__global__ __launch_bounds__(256) void wtrans_kernel(
    const float* __restrict__ Wq, u16* __restrict__ WqT,
    const float* __restrict__ Wk, u16* __restrict__ WkT,
    const float* __restrict__ Wv, u16* __restrict__ WvT,
    const float* __restrict__ Wo, u16* __restrict__ WoT) {
  int z = blockIdx.z;
  const float* in;
  u16* out;
  int C;
  if (z == 0)      { in = Wq; out = WqT; C = 2048; }
  else if (z == 1) { in = Wk; out = WkT; C = 1024; }
  else if (z == 2) { in = Wv; out = WvT; C = 1024; }
  else             { in = Wo; out = WoT; C = 2048; }
  if (blockIdx.x * 32 >= C) return;
  trans_body(in, out, 2048, C);
}

// ---------------- fused RoPE for Q and K, f32 [T][Hh*64] -> bf16 [Hh][T][64] --
__global__ __launch_bounds__(256) void rope2_kernel(const float* __restrict__ QP,
                                                    const float* __restrict__ KP,
                                                    u16* __restrict__ Qh,
                                                    u16* __restrict__ Kh) {
  int hh = blockIdx.y;  // 0..47: 0-31 -> Q half-heads, 32-47 -> K half-heads
  int idx = blockIdx.x * 256 + threadIdx.x;
  int j = idx & 31;
  int t = idx >> 5;
  const float* in;
  u16* out;
  int Hh, hl;
  float scale;
  if (hh < 32) { in = QP; out = Qh; Hh = 32; hl = hh; scale = Q_SCALE; }
  else         { in = KP; out = Kh; Hh = 16; hl = hh - 32; scale = 1.0f; }
  const float* src = in + (size_t)t * (Hh * 64) + hl * 64 + 2 * j;
  float x1 = src[0], x2 = src[1];
  float theta = (float)j * (1.0f / 32.0f);
  float denom = expf(theta * 9.210340371976184f);  // 10000^theta
  float invf = 1.0f / (denom + 1e-8f);
  float ang = (float)t * invf;
  float s = sinf(ang), c = cosf(ang);
  float o1 = (x1 * c - x2 * s) * scale;
  float o2 = (x1 * s + x2 * c) * scale;
  u32 pk = (u32)f2b(o1) | ((u32)f2b(o2) << 16);
  *(u32*)(out + ((size_t)hl * 2048 + t) * 64 + 2 * j) = pk;
}

// ---------------- GEMM body: C[M][N] f32 = A[M][K] bf16 * Bt[N][K] bf16 -------
__device__ __forceinline__ void gemm_body(u16* As, u16* Bs,
                                          const u16* __restrict__ A,
                                          const u16* __restrict__ Bt,
                                          float* __restrict__ C,
                                          int N, int K, int bx, int by) {
  const int tid = threadIdx.x;
  const int lane = tid & 63;
  const int wave = tid >> 6;
  const int m0 = by * 128;
  const int n0 = bx * 128;
  const int wm = (wave >> 1) * 64;
  const int wn = (wave & 1) * 64;
  const int g = lane >> 4, c = lane & 15;

  f32x4 acc[4][4];
#pragma unroll
  for (int i = 0; i < 4; ++i)
#pragma unroll
    for (int j = 0; j < 4; ++j) acc[i][j] = (f32x4){0.f, 0.f, 0.f, 0.f};

  for (int k0 = 0; k0 < K; k0 += 64) {
    __syncthreads();
#pragma unroll
    for (int it = 0; it < 4; ++it) {
      int gi = it * 256 + tid;
      int R = gi >> 3;
      int lg = (gi & 7) ^ (R & 7);
      gll16(A + (size_t)(m0 + R) * K + k0 + lg * 8, As + gi * 8);
      gll16(Bt + (size_t)(n0 + R) * K + k0 + lg * 8, Bs + gi * 8);
    }
    __syncthreads();
#pragma unroll
    for (int kk = 0; kk < 2; ++kk) {
      bf16x8 af[4], bf[4];
#pragma unroll
      for (int i = 0; i < 4; ++i) {
        int ph = ((kk * 4 + g) ^ (c & 7)) * 8;
        af[i] = *(const bf16x8*)&As[(wm + i * 16 + c) * 64 + ph];
        bf[i] = *(const bf16x8*)&Bs[(wn + i * 16 + c) * 64 + ph];
      }
#pragma unroll
      for (int i = 0; i < 4; ++i)
#pragma unroll
        for (int j = 0; j < 4; ++j) acc[i][j] = mfma16(af[i], bf[j], acc[i][j]);
    }
  }
#pragma unroll
  for (int i = 0; i < 4; ++i)
#pragma unroll
    for (int j = 0; j < 4; ++j) {
      int mrow = m0 + wm + i * 16 + g * 4;
      int ncol = n0 + wn + j * 16 + c;
#pragma unroll
      for (int r = 0; r < 4; ++r) C[(size_t)(mrow + r) * N + ncol] = acc[i][j][r];
    }
}

__global__ __launch_bounds__(256, 2) void gemm_qkv_kernel(
    const u16* __restrict__ qb, const u16* __restrict__ WqT, float* __restrict__ QP,
    const u16* __restrict__ kb, const u16* __restrict__ WkT, float* __restrict__ KP,
    const u16* __restrict__ vb, const u16* __restrict__ WvT, float* __restrict__ VP) {
  __shared__ u16 As[128 * 64];
  __shared__ u16 Bs[128 * 64];
  int bid = blockIdx.x;
  if (bid < 256) {
    gemm_body(As, Bs, qb, WqT, QP, 2048, 2048, bid & 15, bid >> 4);
  } else if (bid < 384) {
    int t = bid - 256;
    gemm_body(As, Bs, kb, WkT, KP, 1024, 2048, t & 7, t >> 3);
  } else {
    int t = bid - 384;
    gemm_body(As, Bs, vb, WvT, VP, 1024, 2048, t & 7, t >> 3);
  }
}

__global__ __launch_bounds__(256, 2) void gemm_one_kernel(const u16* __restrict__ A,
                                                          const u16* __restrict__ Bt,
                                                          float* __restrict__ C) {
  __shared__ u16 As[128 * 64];
  __shared__ u16 Bs[128 * 64];
  gemm_body(As, Bs, A, Bt, C, 2048, 2048, blockIdx.x & 15, blockIdx.x >> 4);
}

// ---------------- fused differential flash attention (barrier-free) -----------
// No LDS. K and V read directly as MFMA fragments from global (L1/L2-served).
// Swapped QK: sa = mfma(K, Q) -> lane(g,c) holds P[key=16sf+4g+r][qrow=c].
// PV uses permuted k-slot map key(kk,g,j) = 32kk + 16(j>>2) + 4g + (j&3) so the
// A-operand is each lane's OWN p registers (no cross-lane P movement); the
// V B-fragment is two 8B loads per (f,kk) matching the same map.
__global__ __launch_bounds__(256, 2) void attn_kernel(const u16* __restrict__ Qb,
                                                      const u16* __restrict__ Kb,
                                                      const u16* __restrict__ Vt,
                                                      u16* __restrict__ AO,
                                                      const float* __restrict__ lq1,
                                                      const float* __restrict__ lk1,
                                                      const float* __restrict__ lq2,
                                                      const float* __restrict__ lk2,
                                                      const float* __restrict__ subln) {
  const int b = blockIdx.x;
  const int h = b >> 5;
  const int wave = threadIdx.x >> 6;
  const int lane = threadIdx.x & 63;
  const int t0 = ((b & 31) * 4 + wave) * 16;
  const int g = lane >> 4, c = lane & 15;

  // lambda (wave-parallel)
  float myl1 = lq1[lane] * lk1[lane];
  float myl2 = lq2[lane] * lk2[lane];
#pragma unroll
  for (int off = 32; off; off >>= 1) {
    myl1 += __shfl_xor(myl1, off);
    myl2 += __shfl_xor(myl2, off);
  }
  const float lambda_full = expf(myl1) - expf(myl2) + LAMBDA_INIT_F;

  // Q fragments (B-operand: col = q-row = c, natural d-slots)
  bf16x8 qf[2][2];
#pragma unroll
  for (int e = 0; e < 2; ++e)
#pragma unroll
    for (int d = 0; d < 2; ++d)
      qf[e][d] = *(const bf16x8*)(Qb + ((size_t)(2 * h + e) * 2048 + t0 + c) * 64 + d * 32 + g * 8);

  // per-lane base pointers
  const u16* Kl = Kb + (size_t)h * 2048 * 64 + c * 64 + g * 8;
  const u16* Vl = Vt + (size_t)(h >> 1) * 128 * 2048 + c * 2048 + g * 4;

  f32x4 O[2][8];
#pragma unroll
  for (int e = 0; e < 2; ++e)
#pragma unroll
    for (int f = 0; f < 8; ++f) O[e][f] = (f32x4){0.f, 0.f, 0.f, 0.f};
  float m0 = -1e30f, m1 = -1e30f, ls0 = 0.f, ls1 = 0.f;

  for (int s0 = 0; s0 < 2048; s0 += 64) {
    // K fragments: A-operand rows sf*16+c, natural d-slots
    const u16* Kt = Kl + (size_t)s0 * 64;
    bf16x8 kf[4][2];
#pragma unroll
    for (int sf = 0; sf < 4; ++sf)
#pragma unroll
      for (int d = 0; d < 2; ++d)
        kf[sf][d] = *(const bf16x8*)(Kt + sf * 1024 + d * 32);

    // preload V kk=0 fragments early (latency hides under softmax VALU)
    const u16* Vtile = Vl + s0;
    bf16x4 v0lo[8], v0hi[8];
#pragma unroll
    for (int f = 0; f < 8; ++f) {
      v0lo[f] = *(const bf16x4*)(Vtile + f * 32768);
      v0hi[f] = *(const bf16x4*)(Vtile + f * 32768 + 16);
    }

    bf16x8 paf[2][2];
#pragma unroll
    for (int e = 0; e < 2; ++e) {
      f32x4 sa[4];
#pragma unroll
      for (int sf = 0; sf < 4; ++sf) {
        sa[sf] = (f32x4){0.f, 0.f, 0.f, 0.f};
        sa[sf] = mfma16(kf[sf][0], qf[e][0], sa[sf]);
        sa[sf] = mfma16(kf[sf][1], qf[e][1], sa[sf]);
      }
      float mx = sa[0][0];
#pragma unroll
      for (int sf = 0; sf < 4; ++sf)
#pragma unroll
        for (int r = 0; r < 4; ++r) mx = fmaxf(mx, sa[sf][r]);
      mx = fmaxf(mx, __shfl_xor(mx, 16));
      mx = fmaxf(mx, __shfl_xor(mx, 32));

      float& m_e = e ? m1 : m0;
      float& ls_e = e ? ls1 : ls0;
      if (__any(mx > m_e + THR_LOG2)) {
        float mn = fmaxf(m_e, mx);
        float sc = exp2f(m_e - mn);
        m_e = mn;
        ls_e *= sc;
        float scr[4];
#pragma unroll
        for (int r = 0; r < 4; ++r) scr[r] = __shfl(sc, g * 4 + r);
#pragma unroll
        for (int f = 0; f < 8; ++f)
#pragma unroll
          for (int r = 0; r < 4; ++r) O[e][f][r] *= scr[r];
      }
      float p[4][4];
      float sum = 0.f;
#pragma unroll
      for (int sf = 0; sf < 4; ++sf)
#pragma unroll
        for (int r = 0; r < 4; ++r) {
          float pv = exp2f(sa[sf][r] - m_e);
          p[sf][r] = pv;
          sum += pv;
        }
      sum += __shfl_xor(sum, 16);
      sum += __shfl_xor(sum, 32);
      ls_e += sum;
      paf[e][0] = (bf16x8){(__bf16)p[0][0], (__bf16)p[0][1], (__bf16)p[0][2], (__bf16)p[0][3],
                           (__bf16)p[1][0], (__bf16)p[1][1], (__bf16)p[1][2], (__bf16)p[1][3]};
      paf[e][1] = (bf16x8){(__bf16)p[2][0], (__bf16)p[2][1], (__bf16)p[2][2], (__bf16)p[2][3],
                           (__bf16)p[3][0], (__bf16)p[3][1], (__bf16)p[3][2], (__bf16)p[3][3]};
    }

    // PV: kk=0 from preloaded fragments, kk=1 loaded inline
#pragma unroll
    for (int f = 0; f < 8; ++f) {
      bf16x8 vv = __builtin_shufflevector(v0lo[f], v0hi[f], 0, 1, 2, 3, 4, 5, 6, 7);
      O[0][f] = mfma16(paf[0][0], vv, O[0][f]);
      O[1][f] = mfma16(paf[1][0], vv, O[1][f]);
    }
#pragma unroll
    for (int f = 0; f < 8; ++f) {
      bf16x4 lo = *(const bf16x4*)(Vtile + f * 32768 + 32);
      bf16x4 hi = *(const bf16x4*)(Vtile + f * 32768 + 48);
      bf16x8 vv = __builtin_shufflevector(lo, hi, 0, 1, 2, 3, 4, 5, 6, 7);
      O[0][f] = mfma16(paf[0][1], vv, O[0][f]);
      O[1][f] = mfma16(paf[1][1], vv, O[1][f]);
    }
  }

  // epilogue: redistribute 1/ls from c-layout to (g,r)-layout
  float inv0 = 1.f / ls0, inv1 = 1.f / ls1;
  float i0[4], i1[4];
#pragma unroll
  for (int r = 0; r < 4; ++r) {
    i0[r] = __shfl(inv0, g * 4 + r);
    i1[r] = __shfl(inv1, g * 4 + r);
  }
  float res[8][4];
  float ss[4] = {0.f, 0.f, 0.f, 0.f};
#pragma unroll
  for (int f = 0; f < 8; ++f)
#pragma unroll
    for (int r = 0; r < 4; ++r) {
      float vv = O[0][f][r] * i0[r] - lambda_full * (O[1][f][r] * i1[r]);
      res[f][r] = vv;
      ss[r] += vv * vv;
    }
#pragma unroll
  for (int off = 1; off < 16; off <<= 1)
#pragma unroll
    for (int r = 0; r < 4; ++r) ss[r] += __shfl_xor(ss[r], off);
  float rms[4];
#pragma unroll
  for (int r = 0; r < 4; ++r)
    rms[r] = rsqrtf(ss[r] * (1.0f / 128.0f) + 1e-5f) * ONE_MINUS_LI;
  float w[8];
#pragma unroll
  for (int f = 0; f < 8; ++f) w[f] = subln[f * 16 + c];
#pragma unroll
  for (int f = 0; f < 8; ++f)
#pragma unroll
    for (int r = 0; r < 4; ++r)
      AO[(size_t)(t0 + g * 4 + r) * 2048 + h * 128 + f * 16 + c] = f2b(res[f][r] * rms[r] * w[f]);
}

// ------------------------------------------------------------------------------
extern "C" void kernel_launch(void* const* d_in, const int* in_sizes, int n_in,
                              void* d_out, int out_size, void* d_ws, size_t ws_size,
                              hipStream_t stream) {
  const float* q     = (const float*)d_in[0];
  const float* k     = (const float*)d_in[1];
  const float* v     = (const float*)d_in[2];
  const float* Wq    = (const float*)d_in[3];
  const float* Wk    = (const float*)d_in[4];
  const float* Wv    = (const float*)d_in[5];
  const float* Wout  = (const float*)d_in[6];
  const float* lq1   = (const float*)d_in[7];
  const float* lk1   = (const float*)d_in[8];
  const float* lq2   = (const float*)d_in[9];
  const float* lk2   = (const float*)d_in[10];
  const float* subln = (const float*)d_in[11];
  float* out = (float*)d_out;

  char* ws = (char*)d_ws;
  size_t off = 0;
  auto alloc = [&](size_t bytes) -> void* {
    void* p = ws + off;
    off += (bytes + 255) & ~(size_t)255;
    return p;
  };
  u16* qb  = (u16*)alloc(2048ull * 2048 * 2);
  u16* kb  = (u16*)alloc(2048ull * 2048 * 2);
  u16* vb  = (u16*)alloc(2048ull * 2048 * 2);
  u16* WqT = (u16*)alloc(2048ull * 2048 * 2);
  u16* WkT = (u16*)alloc(1024ull * 2048 * 2);
  u16* WvT = (u16*)alloc(1024ull * 2048 * 2);
  u16* WoT = (u16*)alloc(2048ull * 2048 * 2);
  float* QP = (float*)alloc(2048ull * 2048 * 4);
  float* KP = (float*)alloc(2048ull * 1024 * 4);
  float* VP = (float*)alloc(2048ull * 1024 * 4);
  u16* Qh  = (u16*)alloc(32ull * 2048 * 64 * 2);
  u16* Kh  = (u16*)alloc(16ull * 2048 * 64 * 2);
  u16* Vt  = (u16*)alloc(1024ull * 2048 * 2);
  u16* AO  = (u16*)QP;  // alias: QP dead after rope, AO written later

  // 1. cast inputs to bf16 (one launch)
  cast3_kernel<<<6144, 256, 0, stream>>>(q, k, v, qb, kb, vb);
  // 2. transpose+cast all weights -> [N][K] bf16 (one launch)
  wtrans_kernel<<<dim3(64, 64, 4), 256, 0, stream>>>(Wq, WqT, Wk, WkT, Wv, WvT, Wout, WoT);
  // 3. projections (fused single launch, 512 blocks)
  gemm_qkv_kernel<<<512, 256, 0, stream>>>(qb, WqT, QP, kb, WkT, KP, vb, WvT, VP);
  // 4. RoPE Q+K -> head-major bf16 (one launch; Q pre-scaled by 1/8*log2e)
  rope2_kernel<<<dim3(256, 48), 256, 0, stream>>>(QP, KP, Qh, Kh);
  // 5. V transpose: VP [2048][1024] -> Vt [1024][2048]
  transpose_cast_kernel<<<dim3(32, 64), 256, 0, stream>>>(VP, Vt, 2048, 1024);
  // 6. differential flash attention -> AO bf16 [2048][2048]
  attn_kernel<<<512, 256, 0, stream>>>(Qh, Kh, Vt, AO, lq1, lk1, lq2, lk2, subln);
  // 7. output projection -> f32 d_out
  gemm_one_kernel<<<256, 256, 0, stream>>>(AO, WoT, out);
}

// Round 4
// 195.203 us; speedup vs baseline: 2.0331x; 2.0331x over previous
//
#include <hip/hip_runtime.h>

typedef unsigned short u16;
typedef unsigned int u32;
typedef float f32x4 __attribute__((ext_vector_type(4)));
typedef __bf16 bf16x8 __attribute__((ext_vector_type(8)));
typedef __bf16 bf16x4 __attribute__((ext_vector_type(4)));

#define LAMBDA_INIT_F 0.7836057665316245f
#define ONE_MINUS_LI  0.2163942334683755f
#define THR_LOG2 11.0f
// 0.125 * log2(e): fold softmax base-2 conversion into Q scaling
#define Q_SCALE 0.18033688011112042f

__device__ __forceinline__ u16 f2b(float f) {
  union { float f; u32 u; } x; x.f = f;
  u32 r = x.u + 0x7fffu + ((x.u >> 16) & 1u);
  return (u16)(r >> 16);
}

__device__ __forceinline__ f32x4 mfma16(bf16x8 a, bf16x8 b, f32x4 c) {
  return __builtin_amdgcn_mfma_f32_16x16x32_bf16(a, b, c, 0, 0, 0);
}

// async global->LDS, 16B per lane; LDS dest must be linear in lane order
__device__ __forceinline__ void gll16(const void* gp, void* lp) {
  __builtin_amdgcn_global_load_lds((__attribute__((address_space(1))) void*)(gp),
                                   (__attribute__((address_space(3))) void*)(lp),
                                   16, 0, 0);
}

// ---------------- fused cast f32 -> bf16 for q,k,v (8 elems/thread) -----------
__global__ __launch_bounds__(256) void cast3_kernel(const float* __restrict__ q,
                                                    const float* __restrict__ k,
                                                    const float* __restrict__ v,
                                                    u16* __restrict__ qb,
                                                    u16* __restrict__ kb,
                                                    u16* __restrict__ vb) {
  int bid = blockIdx.x;
  int seg = bid >> 11;
  int i = (bid & 2047) * 256 + threadIdx.x;
  const float* in = seg == 0 ? q : (seg == 1 ? k : v);
  u16* out = seg == 0 ? qb : (seg == 1 ? kb : vb);
  const f32x4* p = (const f32x4*)(in + (size_t)i * 8);
  f32x4 a = p[0], b = p[1];
  union { u16 u[8]; f32x4 v; } o;
#pragma unroll
  for (int j = 0; j < 4; ++j) { o.u[j] = f2b(a[j]); o.u[4 + j] = f2b(b[j]); }
  *(f32x4*)(out + (size_t)i * 8) = o.v;
}

// ------------- tiled transpose+cast: in f32 [R][C] -> out bf16 [C][R] ---------
__device__ __forceinline__ void trans_body(const float* __restrict__ in,
                                           u16* __restrict__ out, int R, int C) {
  __shared__ float tile[32][33];
  int bx = blockIdx.x * 32;  // col base
  int by = blockIdx.y * 32;  // row base
  int tx = threadIdx.x & 31, ty = threadIdx.x >> 5;
#pragma unroll
  for (int i = 0; i < 32; i += 8)
    tile[ty + i][tx] = in[(size_t)(by + ty + i) * C + bx + tx];
  __syncthreads();
#pragma unroll
  for (int i = 0; i < 32; i += 8)
    out[(size_t)(bx + ty + i) * R + by + tx] = f2b(tile[tx][ty + i]);
}

__global__ __launch_bounds__(256) void transpose_cast_kernel(const float* __restrict__ in,
                                                             u16* __restrict__ out,
                                                             int R, int C) {
  trans_body(in, out, R, C);
}

// all 4 weight transposes in one launch (grid.z selects)
__global__ __launch_bounds__(256) void wtrans_kernel(
    const float* __restrict__ Wq, u16* __restrict__ WqT,
    const float* __restrict__ Wk, u16* __restrict__ WkT,
    const float* __restrict__ Wv, u16* __restrict__ WvT,
    const float* __restrict__ Wo, u16* __restrict__ WoT) {
  int z = blockIdx.z;
  const float* in;
  u16* out;
  int C;
  if (z == 0)      { in = Wq; out = WqT; C = 2048; }
  else if (z == 1) { in = Wk; out = WkT; C = 1024; }
  else if (z == 2) { in = Wv; out = WvT; C = 1024; }
  else             { in = Wo; out = WoT; C = 2048; }
  if (blockIdx.x * 32 >= C) return;
  trans_body(in, out, 2048, C);
}

// ---------------- fused RoPE for Q and K, f32 [T][Hh*64] -> bf16 [Hh][T][64] --
__global__ __launch_bounds__(256) void rope2_kernel(const float* __restrict__ QP,
                                                    const float* __restrict__ KP,
                                                    u16* __restrict__ Qh,
                                                    u16* __restrict__ Kh) {
  int hh = blockIdx.y;  // 0..47: 0-31 -> Q half-heads, 32-47 -> K half-heads
  int idx = blockIdx.x * 256 + threadIdx.x;
  int j = idx & 31;
  int t = idx >> 5;
  const float* in;
  u16* out;
  int Hh, hl;
  float scale;
  if (hh < 32) { in = QP; out = Qh; Hh = 32; hl = hh; scale = Q_SCALE; }
  else         { in = KP; out = Kh; Hh = 16; hl = hh - 32; scale = 1.0f; }
  const float* src = in + (size_t)t * (Hh * 64) + hl * 64 + 2 * j;
  float x1 = src[0], x2 = src[1];
  float theta = (float)j * (1.0f / 32.0f);
  float denom = expf(theta * 9.210340371976184f);  // 10000^theta
  float invf = 1.0f / (denom + 1e-8f);
  float ang = (float)t * invf;
  float s = sinf(ang), c = cosf(ang);
  float o1 = (x1 * c - x2 * s) * scale;
  float o2 = (x1 * s + x2 * c) * scale;
  u32 pk = (u32)f2b(o1) | ((u32)f2b(o2) << 16);
  *(u32*)(out + ((size_t)hl * 2048 + t) * 64 + 2 * j) = pk;
}

// ---------------- GEMM body: C[M][N] f32 = A[M][K] bf16 * Bt[N][K] bf16 -------
__device__ __forceinline__ void gemm_body(u16* As, u16* Bs,
                                          const u16* __restrict__ A,
                                          const u16* __restrict__ Bt,
                                          float* __restrict__ C,
                                          int N, int K, int bx, int by) {
  const int tid = threadIdx.x;
  const int lane = tid & 63;
  const int wave = tid >> 6;
  const int m0 = by * 128;
  const int n0 = bx * 128;
  const int wm = (wave >> 1) * 64;
  const int wn = (wave & 1) * 64;
  const int g = lane >> 4, c = lane & 15;

  f32x4 acc[4][4];
#pragma unroll
  for (int i = 0; i < 4; ++i)
#pragma unroll
    for (int j = 0; j < 4; ++j) acc[i][j] = (f32x4){0.f, 0.f, 0.f, 0.f};

  for (int k0 = 0; k0 < K; k0 += 64) {
    __syncthreads();
#pragma unroll
    for (int it = 0; it < 4; ++it) {
      int gi = it * 256 + tid;
      int R = gi >> 3;
      int lg = (gi & 7) ^ (R & 7);
      gll16(A + (size_t)(m0 + R) * K + k0 + lg * 8, As + gi * 8);
      gll16(Bt + (size_t)(n0 + R) * K + k0 + lg * 8, Bs + gi * 8);
    }
    __syncthreads();
#pragma unroll
    for (int kk = 0; kk < 2; ++kk) {
      bf16x8 af[4], bf[4];
#pragma unroll
      for (int i = 0; i < 4; ++i) {
        int ph = ((kk * 4 + g) ^ (c & 7)) * 8;
        af[i] = *(const bf16x8*)&As[(wm + i * 16 + c) * 64 + ph];
        bf[i] = *(const bf16x8*)&Bs[(wn + i * 16 + c) * 64 + ph];
      }
#pragma unroll
      for (int i = 0; i < 4; ++i)
#pragma unroll
        for (int j = 0; j < 4; ++j) acc[i][j] = mfma16(af[i], bf[j], acc[i][j]);
    }
  }
#pragma unroll
  for (int i = 0; i < 4; ++i)
#pragma unroll
    for (int j = 0; j < 4; ++j) {
      int mrow = m0 + wm + i * 16 + g * 4;
      int ncol = n0 + wn + j * 16 + c;
#pragma unroll
      for (int r = 0; r < 4; ++r) C[(size_t)(mrow + r) * N + ncol] = acc[i][j][r];
    }
}

__global__ __launch_bounds__(256, 2) void gemm_qkv_kernel(
    const u16* __restrict__ qb, const u16* __restrict__ WqT, float* __restrict__ QP,
    const u16* __restrict__ kb, const u16* __restrict__ WkT, float* __restrict__ KP,
    const u16* __restrict__ vb, const u16* __restrict__ WvT, float* __restrict__ VP) {
  __shared__ u16 As[128 * 64];
  __shared__ u16 Bs[128 * 64];
  // XCD-aware swizzle: 512 blocks, 64 consecutive work-ids per XCD
  int bid = ((blockIdx.x & 7) << 6) | (blockIdx.x >> 3);
  if (bid < 256) {
    gemm_body(As, Bs, qb, WqT, QP, 2048, 2048, bid & 15, bid >> 4);
  } else if (bid < 384) {
    int t = bid - 256;
    gemm_body(As, Bs, kb, WkT, KP, 1024, 2048, t & 7, t >> 3);
  } else {
    int t = bid - 384;
    gemm_body(As, Bs, vb, WvT, VP, 1024, 2048, t & 7, t >> 3);
  }
}

__global__ __launch_bounds__(256, 2) void gemm_one_kernel(const u16* __restrict__ A,
                                                          const u16* __restrict__ Bt,
                                                          float* __restrict__ C) {
  __shared__ u16 As[128 * 64];
  __shared__ u16 Bs[128 * 64];
  int bid = ((blockIdx.x & 7) << 5) | (blockIdx.x >> 3);
  gemm_body(As, Bs, A, Bt, C, 2048, 2048, bid & 15, bid >> 4);
}

// ---------------- fused differential flash attention --------------------------
// R2 LDS-staging skeleton + R3 register-P PV (both HW-verified):
//  - K/V double-buffered in LDS (gll16 w=16, granule-XOR swizzled source).
//  - Swapped QK: sa = mfma(K, Q) -> lane(g,c) holds P[key=16sf+4g+r][qrow=c].
//  - PV A-operand = lane's OWN packed p regs via permuted k-slot map
//    key(kk,g,j) = 32kk + 16(j>>2) + 4g + (j&3); V B-fragment = 2x ds_read_b64
//    per (f,kk) from the XOR-swizzled Vs (2-way bank = free per quarter-wave).
// grid: 16 heads * 32 qblocks (XCD-swizzled), block 256 (4 waves x 16 q-rows).
__global__ __launch_bounds__(256, 2) void attn_kernel(const u16* __restrict__ Qb,
                                                      const u16* __restrict__ Kb,
                                                      const u16* __restrict__ Vt,
                                                      u16* __restrict__ AO,
                                                      const float* __restrict__ lq1,
                                                      const float* __restrict__ lk1,
                                                      const float* __restrict__ lq2,
                                                      const float* __restrict__ lk2,
                                                      const float* __restrict__ subln) {
  // XCD swizzle: 64 consecutive work-ids (2 heads, ~1MB K/V) per XCD's L2
  const int b = ((blockIdx.x & 7) << 6) | (blockIdx.x >> 3);
  const int h = b >> 5;
  const int wave = threadIdx.x >> 6;
  const int lane = threadIdx.x & 63;
  const int t0 = ((b & 31) * 4 + wave) * 16;
  const int g = lane >> 4, c = lane & 15;

  __shared__ u16 Ks[2][64 * 64];    // [buf][key][d]   8KB each
  __shared__ u16 Vs[2][128 * 64];   // [buf][dv][key]  16KB each (granule-XOR)

  const u16* Kh = Kb + (size_t)h * 2048 * 64;
  const u16* Vh = Vt + (size_t)(h >> 1) * 128 * 2048;

  // lambda (wave-parallel)
  float myl1 = lq1[lane] * lk1[lane];
  float myl2 = lq2[lane] * lk2[lane];
#pragma unroll
  for (int off = 32; off; off >>= 1) {
    myl1 += __shfl_xor(myl1, off);
    myl2 += __shfl_xor(myl2, off);
  }
  const float lambda_full = expf(myl1) - expf(myl2) + LAMBDA_INIT_F;

  // Q fragments (B-operand: col = q-row = c, natural d-slots)
  bf16x8 qf[2][2];
#pragma unroll
  for (int e = 0; e < 2; ++e)
#pragma unroll
    for (int d = 0; d < 2; ++d)
      qf[e][d] = *(const bf16x8*)(Qb + ((size_t)(2 * h + e) * 2048 + t0 + c) * 64 + d * 32 + g * 8);

  f32x4 O[2][8];
#pragma unroll
  for (int e = 0; e < 2; ++e)
#pragma unroll
    for (int f = 0; f < 8; ++f) O[e][f] = (f32x4){0.f, 0.f, 0.f, 0.f};
  float m0 = -1e30f, m1 = -1e30f, ls0 = 0.f, ls1 = 0.f;

#define STAGE(buf, s0)                                                        \
  {                                                                           \
    _Pragma("unroll") for (int it = 0; it < 2; ++it) {                        \
      int gi = it * 256 + threadIdx.x;                                        \
      int R = gi >> 3;                                                        \
      int lg = (gi & 7) ^ (R & 7);                                            \
      gll16(Kh + (size_t)((s0) + R) * 64 + lg * 8, &Ks[buf][gi * 8]);         \
    }                                                                         \
    _Pragma("unroll") for (int it = 0; it < 4; ++it) {                        \
      int gi = it * 256 + threadIdx.x;                                        \
      int R = gi >> 3;                                                        \
      int lg = (gi & 7) ^ (R & 7);                                            \
      gll16(Vh + (size_t)R * 2048 + (s0) + lg * 8, &Vs[buf][gi * 8]);         \
    }                                                                         \
  }

  STAGE(0, 0);

  for (int t = 0; t < 32; ++t) {
    const int cur = t & 1;
    __syncthreads();  // drains vmcnt: buf `cur` staged & all waves done with cur^1
    if (t < 31) STAGE(cur ^ 1, (t + 1) * 64);

    const u16* K0 = Ks[cur];
    const u16* V0 = Vs[cur];

    // K fragments (A-operand: row = key), shared across both sub-heads
    bf16x8 kf[4][2];
#pragma unroll
    for (int sf = 0; sf < 4; ++sf)
#pragma unroll
      for (int d = 0; d < 2; ++d) {
        int ph = ((d * 4 + g) ^ (c & 7)) * 8;
        kf[sf][d] = *(const bf16x8*)&K0[(sf * 16 + c) * 64 + ph];
      }

    // QK^T for both sub-heads up-front (ILP across e)
    f32x4 sa[2][4];
#pragma unroll
    for (int e = 0; e < 2; ++e)
#pragma unroll
      for (int sf = 0; sf < 4; ++sf) {
        f32x4 z = (f32x4){0.f, 0.f, 0.f, 0.f};
        z = mfma16(kf[sf][0], qf[e][0], z);
        z = mfma16(kf[sf][1], qf[e][1], z);
        sa[e][sf] = z;
      }

    // softmax per sub-head -> packed register P fragments
    bf16x8 paf[2][2];
#pragma unroll
    for (int e = 0; e < 2; ++e) {
      float mx0 = fmaxf(fmaxf(sa[e][0][0], sa[e][0][1]), fmaxf(sa[e][0][2], sa[e][0][3]));
      float mx1 = fmaxf(fmaxf(sa[e][1][0], sa[e][1][1]), fmaxf(sa[e][1][2], sa[e][1][3]));
      float mx2 = fmaxf(fmaxf(sa[e][2][0], sa[e][2][1]), fmaxf(sa[e][2][2], sa[e][2][3]));
      float mx3 = fmaxf(fmaxf(sa[e][3][0], sa[e][3][1]), fmaxf(sa[e][3][2], sa[e][3][3]));
      float mx = fmaxf(fmaxf(mx0, mx1), fmaxf(mx2, mx3));
      mx = fmaxf(mx, __shfl_xor(mx, 16));
      mx = fmaxf(mx, __shfl_xor(mx, 32));

      float& m_e = e ? m1 : m0;
      float& ls_e = e ? ls1 : ls0;
      if (__any(mx > m_e + THR_LOG2)) {
        float mn = fmaxf(m_e, mx);
        float sc = exp2f(m_e - mn);
        m_e = mn;
        ls_e *= sc;
        float scr[4];
#pragma unroll
        for (int r = 0; r < 4; ++r) scr[r] = __shfl(sc, g * 4 + r);
#pragma unroll
        for (int f = 0; f < 8; ++f)
#pragma unroll
          for (int r = 0; r < 4; ++r) O[e][f][r] *= scr[r];
      }
      float p[4][4];
      float sum = 0.f;
#pragma unroll
      for (int sf = 0; sf < 4; ++sf)
#pragma unroll
        for (int r = 0; r < 4; ++r) {
          float pv = exp2f(sa[e][sf][r] - m_e);
          p[sf][r] = pv;
          sum += pv;
        }
      sum += __shfl_xor(sum, 16);
      sum += __shfl_xor(sum, 32);
      ls_e += sum;
      paf[e][0] = (bf16x8){(__bf16)p[0][0], (__bf16)p[0][1], (__bf16)p[0][2], (__bf16)p[0][3],
                           (__bf16)p[1][0], (__bf16)p[1][1], (__bf16)p[1][2], (__bf16)p[1][3]};
      paf[e][1] = (bf16x8){(__bf16)p[2][0], (__bf16)p[2][1], (__bf16)p[2][2], (__bf16)p[2][3],
                           (__bf16)p[3][0], (__bf16)p[3][1], (__bf16)p[3][2], (__bf16)p[3][3]};
    }

    // PV from LDS with permuted k-slot map (A = lane's own paf regs)
    __builtin_amdgcn_s_setprio(1);
#pragma unroll
    for (int f = 0; f < 8; ++f) {
      int dvrow = (f * 16 + c) * 64;
#pragma unroll
      for (int kk = 0; kk < 2; ++kk) {
        bf16x4 lo = *(const bf16x4*)&V0[dvrow + (((4 * kk + (g >> 1)) ^ (c & 7)) << 3) + (g & 1) * 4];
        bf16x4 hi = *(const bf16x4*)&V0[dvrow + (((4 * kk + 2 + (g >> 1)) ^ (c & 7)) << 3) + (g & 1) * 4];
        bf16x8 vv = __builtin_shufflevector(lo, hi, 0, 1, 2, 3, 4, 5, 6, 7);
        O[0][f] = mfma16(paf[0][kk], vv, O[0][f]);
        O[1][f] = mfma16(paf[1][kk], vv, O[1][f]);
      }
    }
    __builtin_amdgcn_s_setprio(0);
  }

  // epilogue: redistribute 1/ls from c-layout to (g,r)-layout
  float inv0 = 1.f / ls0, inv1 = 1.f / ls1;
  float i0[4], i1[4];
#pragma unroll
  for (int r = 0; r < 4; ++r) {
    i0[r] = __shfl(inv0, g * 4 + r);
    i1[r] = __shfl(inv1, g * 4 + r);
  }
  float res[8][4];
  float ss[4] = {0.f, 0.f, 0.f, 0.f};
#pragma unroll
  for (int f = 0; f < 8; ++f)
#pragma unroll
    for (int r = 0; r < 4; ++r) {
      float vv = O[0][f][r] * i0[r] - lambda_full * (O[1][f][r] * i1[r]);
      res[f][r] = vv;
      ss[r] += vv * vv;
    }
#pragma unroll
  for (int off = 1; off < 16; off <<= 1)
#pragma unroll
    for (int r = 0; r < 4; ++r) ss[r] += __shfl_xor(ss[r], off);
  float rms[4];
#pragma unroll
  for (int r = 0; r < 4; ++r)
    rms[r] = rsqrtf(ss[r] * (1.0f / 128.0f) + 1e-5f) * ONE_MINUS_LI;
  float w[8];
#pragma unroll
  for (int f = 0; f < 8; ++f) w[f] = subln[f * 16 + c];
#pragma unroll
  for (int f = 0; f < 8; ++f)
#pragma unroll
    for (int r = 0; r < 4; ++r)
      AO[(size_t)(t0 + g * 4 + r) * 2048 + h * 128 + f * 16 + c] = f2b(res[f][r] * rms[r] * w[f]);
}

// ------------------------------------------------------------------------------
extern "C" void kernel_launch(void* const* d_in, const int* in_sizes, int n_in,
                              void* d_out, int out_size, void* d_ws, size_t ws_size,
                              hipStream_t stream) {
  const float* q     = (const float*)d_in[0];
  const float* k     = (const float*)d_in[1];
  const float* v     = (const float*)d_in[2];
  const float* Wq    = (const float*)d_in[3];
  const float* Wk    = (const float*)d_in[4];
  const float* Wv    = (const float*)d_in[5];
  const float* Wout  = (const float*)d_in[6];
  const float* lq1   = (const float*)d_in[7];
  const float* lk1   = (const float*)d_in[8];
  const float* lq2   = (const float*)d_in[9];
  const float* lk2   = (const float*)d_in[10];
  const float* subln = (const float*)d_in[11];
  float* out = (float*)d_out;

  char* ws = (char*)d_ws;
  size_t off = 0;
  auto alloc = [&](size_t bytes) -> void* {
    void* p = ws + off;
    off += (bytes + 255) & ~(size_t)255;
    return p;
  };
  u16* qb  = (u16*)alloc(2048ull * 2048 * 2);
  u16* kb  = (u16*)alloc(2048ull * 2048 * 2);
  u16* vb  = (u16*)alloc(2048ull * 2048 * 2);
  u16* WqT = (u16*)alloc(2048ull * 2048 * 2);
  u16* WkT = (u16*)alloc(1024ull * 2048 * 2);
  u16* WvT = (u16*)alloc(1024ull * 2048 * 2);
  u16* WoT = (u16*)alloc(2048ull * 2048 * 2);
  float* QP = (float*)alloc(2048ull * 2048 * 4);
  float* KP = (float*)alloc(2048ull * 1024 * 4);
  float* VP = (float*)alloc(2048ull * 1024 * 4);
  u16* Qh  = (u16*)alloc(32ull * 2048 * 64 * 2);
  u16* Kh  = (u16*)alloc(16ull * 2048 * 64 * 2);
  u16* Vt  = (u16*)alloc(1024ull * 2048 * 2);
  u16* AO  = (u16*)QP;  // alias: QP dead after rope, AO written later

  // 1. cast inputs to bf16 (one launch)
  cast3_kernel<<<6144, 256, 0, stream>>>(q, k, v, qb, kb, vb);
  // 2. transpose+cast all weights -> [N][K] bf16 (one launch)
  wtrans_kernel<<<dim3(64, 64, 4), 256, 0, stream>>>(Wq, WqT, Wk, WkT, Wv, WvT, Wout, WoT);
  // 3. projections (fused single launch, 512 blocks, XCD-swizzled)
  gemm_qkv_kernel<<<512, 256, 0, stream>>>(qb, WqT, QP, kb, WkT, KP, vb, WvT, VP);
  // 4. RoPE Q+K -> head-major bf16 (one launch; Q pre-scaled by 1/8*log2e)
  rope2_kernel<<<dim3(256, 48), 256, 0, stream>>>(QP, KP, Qh, Kh);
  // 5. V transpose: VP [2048][1024] -> Vt [1024][2048]
  transpose_cast_kernel<<<dim3(32, 64), 256, 0, stream>>>(VP, Vt, 2048, 1024);
  // 6. differential flash attention -> AO bf16 [2048][2048]
  attn_kernel<<<512, 256, 0, stream>>>(Qh, Kh, Vt, AO, lq1, lk1, lq2, lk2, subln);
  // 7. output projection -> f32 d_out
  gemm_one_kernel<<<256, 256, 0, stream>>>(AO, WoT, out);
}

// Round 5
// 192.145 us; speedup vs baseline: 2.0654x; 1.0159x over previous
//
#include <hip/hip_runtime.h>

typedef unsigned short u16;
typedef unsigned int u32;
typedef float f32x4 __attribute__((ext_vector_type(4)));
typedef __bf16 bf16x8 __attribute__((ext_vector_type(8)));
typedef __bf16 bf16x4 __attribute__((ext_vector_type(4)));

#define LAMBDA_INIT_F 0.7836057665316245f
#define ONE_MINUS_LI  0.2163942334683755f
#define THR_LOG2 11.0f
// 0.125 * log2(e): fold softmax base-2 conversion into Q scaling
#define Q_SCALE 0.18033688011112042f

__device__ __forceinline__ u16 f2b(float f) {
  union { float f; u32 u; } x; x.f = f;
  u32 r = x.u + 0x7fffu + ((x.u >> 16) & 1u);
  return (u16)(r >> 16);
}

__device__ __forceinline__ f32x4 mfma16(bf16x8 a, bf16x8 b, f32x4 c) {
  return __builtin_amdgcn_mfma_f32_16x16x32_bf16(a, b, c, 0, 0, 0);
}

// async global->LDS, 16B per lane; LDS dest must be linear in lane order
__device__ __forceinline__ void gll16(const void* gp, void* lp) {
  __builtin_amdgcn_global_load_lds((__attribute__((address_space(1))) void*)(gp),
                                   (__attribute__((address_space(3))) void*)(lp),
                                   16, 0, 0);
}

// ---------------- fused cast f32 -> bf16 for q,k,v (8 elems/thread) -----------
__global__ __launch_bounds__(256) void cast3_kernel(const float* __restrict__ q,
                                                    const float* __restrict__ k,
                                                    const float* __restrict__ v,
                                                    u16* __restrict__ qb,
                                                    u16* __restrict__ kb,
                                                    u16* __restrict__ vb) {
  int bid = blockIdx.x;
  int seg = bid >> 11;
  int i = (bid & 2047) * 256 + threadIdx.x;
  const float* in = seg == 0 ? q : (seg == 1 ? k : v);
  u16* out = seg == 0 ? qb : (seg == 1 ? kb : vb);
  const f32x4* p = (const f32x4*)(in + (size_t)i * 8);
  f32x4 a = p[0], b = p[1];
  union { u16 u[8]; f32x4 v; } o;
#pragma unroll
  for (int j = 0; j < 4; ++j) { o.u[j] = f2b(a[j]); o.u[4 + j] = f2b(b[j]); }
  *(f32x4*)(out + (size_t)i * 8) = o.v;
}

// ------------- tiled transpose+cast: in f32 [R][C] -> out bf16 [C][R] ---------
__device__ __forceinline__ void trans_body(const float* __restrict__ in,
                                           u16* __restrict__ out, int R, int C) {
  __shared__ float tile[32][33];
  int bx = blockIdx.x * 32;  // col base
  int by = blockIdx.y * 32;  // row base
  int tx = threadIdx.x & 31, ty = threadIdx.x >> 5;
#pragma unroll
  for (int i = 0; i < 32; i += 8)
    tile[ty + i][tx] = in[(size_t)(by + ty + i) * C + bx + tx];
  __syncthreads();
#pragma unroll
  for (int i = 0; i < 32; i += 8)
    out[(size_t)(bx + ty + i) * R + by + tx] = f2b(tile[tx][ty + i]);
}

__global__ __launch_bounds__(256) void transpose_cast_kernel(const float* __restrict__ in,
                                                             u16* __restrict__ out,
                                                             int R, int C) {
  trans_body(in, out, R, C);
}

// all 4 weight transposes in one launch (grid.z selects)
__global__ __launch_bounds__(256) void wtrans_kernel(
    const float* __restrict__ Wq, u16* __restrict__ WqT,
    const float* __restrict__ Wk, u16* __restrict__ WkT,
    const float* __restrict__ Wv, u16* __restrict__ WvT,
    const float* __restrict__ Wo, u16* __restrict__ WoT) {
  int z = blockIdx.z;
  const float* in;
  u16* out;
  int C;
  if (z == 0)      { in = Wq; out = WqT; C = 2048; }
  else if (z == 1) { in = Wk; out = WkT; C = 1024; }
  else if (z == 2) { in = Wv; out = WvT; C = 1024; }
  else             { in = Wo; out = WoT; C = 2048; }
  if (blockIdx.x * 32 >= C) return;
  trans_body(in, out, 2048, C);
}

// ---------------- fused RoPE for Q and K, f32 [T][Hh*64] -> bf16 [Hh][T][64] --
__global__ __launch_bounds__(256) void rope2_kernel(const float* __restrict__ QP,
                                                    const float* __restrict__ KP,
                                                    u16* __restrict__ Qh,
                                                    u16* __restrict__ Kh) {
  int hh = blockIdx.y;  // 0..47: 0-31 -> Q half-heads, 32-47 -> K half-heads
  int idx = blockIdx.x * 256 + threadIdx.x;
  int j = idx & 31;
  int t = idx >> 5;
  const float* in;
  u16* out;
  int Hh, hl;
  float scale;
  if (hh < 32) { in = QP; out = Qh; Hh = 32; hl = hh; scale = Q_SCALE; }
  else         { in = KP; out = Kh; Hh = 16; hl = hh - 32; scale = 1.0f; }
  const float* src = in + (size_t)t * (Hh * 64) + hl * 64 + 2 * j;
  float x1 = src[0], x2 = src[1];
  float theta = (float)j * (1.0f / 32.0f);
  float denom = expf(theta * 9.210340371976184f);  // 10000^theta
  float invf = 1.0f / (denom + 1e-8f);
  float ang = (float)t * invf;
  float s = sinf(ang), c = cosf(ang);
  float o1 = (x1 * c - x2 * s) * scale;
  float o2 = (x1 * s + x2 * c) * scale;
  u32 pk = (u32)f2b(o1) | ((u32)f2b(o2) << 16);
  *(u32*)(out + ((size_t)hl * 2048 + t) * 64 + 2 * j) = pk;
}

// ---------------- GEMM body: C[M][N] f32 = A[M][K] bf16 * Bt[N][K] bf16 -------
__device__ __forceinline__ void gemm_body(u16* As, u16* Bs,
                                          const u16* __restrict__ A,
                                          const u16* __restrict__ Bt,
                                          float* __restrict__ C,
                                          int N, int K, int bx, int by) {
  const int tid = threadIdx.x;
  const int lane = tid & 63;
  const int wave = tid >> 6;
  const int m0 = by * 128;
  const int n0 = bx * 128;
  const int wm = (wave >> 1) * 64;
  const int wn = (wave & 1) * 64;
  const int g = lane >> 4, c = lane & 15;

  f32x4 acc[4][4];
#pragma unroll
  for (int i = 0; i < 4; ++i)
#pragma unroll
    for (int j = 0; j < 4; ++j) acc[i][j] = (f32x4){0.f, 0.f, 0.f, 0.f};

  for (int k0 = 0; k0 < K; k0 += 64) {
    __syncthreads();
#pragma unroll
    for (int it = 0; it < 4; ++it) {
      int gi = it * 256 + tid;
      int R = gi >> 3;
      int lg = (gi & 7) ^ (R & 7);
      gll16(A + (size_t)(m0 + R) * K + k0 + lg * 8, As + gi * 8);
      gll16(Bt + (size_t)(n0 + R) * K + k0 + lg * 8, Bs + gi * 8);
    }
    __syncthreads();
#pragma unroll
    for (int kk = 0; kk < 2; ++kk) {
      bf16x8 af[4], bf[4];
#pragma unroll
      for (int i = 0; i < 4; ++i) {
        int ph = ((kk * 4 + g) ^ (c & 7)) * 8;
        af[i] = *(const bf16x8*)&As[(wm + i * 16 + c) * 64 + ph];
        bf[i] = *(const bf16x8*)&Bs[(wn + i * 16 + c) * 64 + ph];
      }
#pragma unroll
      for (int i = 0; i < 4; ++i)
#pragma unroll
        for (int j = 0; j < 4; ++j) acc[i][j] = mfma16(af[i], bf[j], acc[i][j]);
    }
  }
#pragma unroll
  for (int i = 0; i < 4; ++i)
#pragma unroll
    for (int j = 0; j < 4; ++j) {
      int mrow = m0 + wm + i * 16 + g * 4;
      int ncol = n0 + wn + j * 16 + c;
#pragma unroll
      for (int r = 0; r < 4; ++r) C[(size_t)(mrow + r) * N + ncol] = acc[i][j][r];
    }
}

__global__ __launch_bounds__(256, 2) void gemm_qkv_kernel(
    const u16* __restrict__ qb, const u16* __restrict__ WqT, float* __restrict__ QP,
    const u16* __restrict__ kb, const u16* __restrict__ WkT, float* __restrict__ KP,
    const u16* __restrict__ vb, const u16* __restrict__ WvT, float* __restrict__ VP) {
  __shared__ u16 As[128 * 64];
  __shared__ u16 Bs[128 * 64];
  // XCD-aware swizzle: 512 blocks, 64 consecutive work-ids per XCD
  int bid = ((blockIdx.x & 7) << 6) | (blockIdx.x >> 3);
  if (bid < 256) {
    gemm_body(As, Bs, qb, WqT, QP, 2048, 2048, bid & 15, bid >> 4);
  } else if (bid < 384) {
    int t = bid - 256;
    gemm_body(As, Bs, kb, WkT, KP, 1024, 2048, t & 7, t >> 3);
  } else {
    int t = bid - 384;
    gemm_body(As, Bs, vb, WvT, VP, 1024, 2048, t & 7, t >> 3);
  }
}

__global__ __launch_bounds__(256, 2) void gemm_one_kernel(const u16* __restrict__ A,
                                                          const u16* __restrict__ Bt,
                                                          float* __restrict__ C) {
  __shared__ u16 As[128 * 64];
  __shared__ u16 Bs[128 * 64];
  int bid = ((blockIdx.x & 7) << 5) | (blockIdx.x >> 3);
  gemm_body(As, Bs, A, Bt, C, 2048, 2048, bid & 15, bid >> 4);
}

// ---------------- fused differential flash attention --------------------------
// R4 structure (HW-verified math), micro-optimized:
//  - KV loop unrolled x2 -> all LDS addresses = per-lane base reg + 16-bit imm
//    (single smem block: K buf0@0, buf1@4096, V buf0@8192, buf1@16384 elems).
//  - XOR-granule variation folded into 6 precomputed base regs (kb0/kb1 for K
//    d-slots, vb00/01/10/11 for V lo/hi x kk) -- XOR constants hit disjoint
//    address bits, so base ^ const == base + imm-safe variant per buffer.
//  - Fragment loads batched: 8x K b128 before QK; 16x V(kk=0) b64 issued before
//    softmax (latency under VALU); V(kk=1) issued under PV kk=0 MFMAs.
__global__ __launch_bounds__(256, 2) void attn_kernel(const u16* __restrict__ Qb,
                                                      const u16* __restrict__ Kb,
                                                      const u16* __restrict__ Vt,
                                                      u16* __restrict__ AO,
                                                      const float* __restrict__ lq1,
                                                      const float* __restrict__ lk1,
                                                      const float* __restrict__ lq2,
                                                      const float* __restrict__ lk2,
                                                      const float* __restrict__ subln) {
  // XCD swizzle: 64 consecutive work-ids (2 heads, ~1MB K/V) per XCD's L2
  const int b = ((blockIdx.x & 7) << 6) | (blockIdx.x >> 3);
  const int h = b >> 5;
  const int tid = threadIdx.x;
  const int wave = tid >> 6;
  const int lane = tid & 63;
  const int t0 = ((b & 31) * 4 + wave) * 16;
  const int g = lane >> 4, c = lane & 15;
  const int c7 = c & 7, g0 = g & 1, g1 = g >> 1;

  __shared__ u16 smem[24576];  // 48KB

  const u16* Kh = Kb + (size_t)h * 2048 * 64;
  const u16* Vh = Vt + (size_t)(h >> 1) * 128 * 2048;

  // lambda (wave-parallel)
  float myl1 = lq1[lane] * lk1[lane];
  float myl2 = lq2[lane] * lk2[lane];
#pragma unroll
  for (int off = 32; off; off >>= 1) {
    myl1 += __shfl_xor(myl1, off);
    myl2 += __shfl_xor(myl2, off);
  }
  const float lambda_full = expf(myl1) - expf(myl2) + LAMBDA_INIT_F;

  // Q fragments (B-operand: col = q-row = c, natural d-slots)
  bf16x8 qf[2][2];
#pragma unroll
  for (int e = 0; e < 2; ++e)
#pragma unroll
    for (int d = 0; d < 2; ++d)
      qf[e][d] = *(const bf16x8*)(Qb + ((size_t)(2 * h + e) * 2048 + t0 + c) * 64 + d * 32 + g * 8);

  // loop-invariant LDS read bases (u16-elem units)
  const int kb0 = c * 64 + ((g ^ c7) * 8);
  const int kb1 = kb0 ^ 32;  // d=1 flips granule bit2 -> elem bit5
  const int vb00 = c * 64 + ((g1 ^ (c7 & 1)) << 3) + ((c7 & 2) << 3) + ((c7 & 4) << 3) + g0 * 4;
  const int vb01 = vb00 ^ 16;  // hi granule
  const int vb10 = vb00 ^ 32;  // kk=1 lo
  const int vb11 = vb00 ^ 48;  // kk=1 hi

  // per-thread stage source bases
  const u16* ksrc0;
  const u16* ksrc1;
  const u16* vsrc0;
  const u16* vsrc1;
  const u16* vsrc2;
  const u16* vsrc3;
  { int gi = tid;       int R = gi >> 3; ksrc0 = Kh + R * 64 + ((gi & 7) ^ (R & 7)) * 8; }
  { int gi = 256 + tid; int R = gi >> 3; ksrc1 = Kh + R * 64 + ((gi & 7) ^ (R & 7)) * 8; }
  { int gi = tid;       int R = gi >> 3; vsrc0 = Vh + (size_t)R * 2048 + ((gi & 7) ^ (R & 7)) * 8; }
  { int gi = 256 + tid; int R = gi >> 3; vsrc1 = Vh + (size_t)R * 2048 + ((gi & 7) ^ (R & 7)) * 8; }
  { int gi = 512 + tid; int R = gi >> 3; vsrc2 = Vh + (size_t)R * 2048 + ((gi & 7) ^ (R & 7)) * 8; }
  { int gi = 768 + tid; int R = gi >> 3; vsrc3 = Vh + (size_t)R * 2048 + ((gi & 7) ^ (R & 7)) * 8; }

  f32x4 O[2][8];
#pragma unroll
  for (int e = 0; e < 2; ++e)
#pragma unroll
    for (int f = 0; f < 8; ++f) O[e][f] = (f32x4){0.f, 0.f, 0.f, 0.f};
  float m0 = -1e30f, m1 = -1e30f, ls0 = 0.f, ls1 = 0.f;

#define STAGE(kOff, vOff, s0)                                   \
  do {                                                          \
    gll16(ksrc0 + (size_t)(s0) * 64, smem + (kOff) + tid * 8);  \
    gll16(ksrc1 + (size_t)(s0) * 64, smem + (kOff) + 2048 + tid * 8); \
    gll16(vsrc0 + (s0), smem + (vOff) + tid * 8);               \
    gll16(vsrc1 + (s0), smem + (vOff) + 2048 + tid * 8);        \
    gll16(vsrc2 + (s0), smem + (vOff) + 4096 + tid * 8);        \
    gll16(vsrc3 + (s0), smem + (vOff) + 6144 + tid * 8);        \
  } while (0)

#define TILE(kOff, vOff)                                                      \
  do {                                                                        \
    bf16x8 kf[4][2];                                                          \
    _Pragma("unroll") for (int sf = 0; sf < 4; ++sf) {                        \
      kf[sf][0] = *(const bf16x8*)&smem[(kOff) + kb0 + sf * 1024];            \
      kf[sf][1] = *(const bf16x8*)&smem[(kOff) + kb1 + sf * 1024];            \
    }                                                                         \
    f32x4 sa[2][4];                                                           \
    _Pragma("unroll") for (int e = 0; e < 2; ++e)                             \
      _Pragma("unroll") for (int sf = 0; sf < 4; ++sf) {                      \
        f32x4 z = (f32x4){0.f, 0.f, 0.f, 0.f};                                \
        z = mfma16(kf[sf][0], qf[e][0], z);                                   \
        z = mfma16(kf[sf][1], qf[e][1], z);                                   \
        sa[e][sf] = z;                                                        \
      }                                                                       \
    bf16x4 vlo0[8], vhi0[8];                                                  \
    _Pragma("unroll") for (int f = 0; f < 8; ++f) {                           \
      vlo0[f] = *(const bf16x4*)&smem[(vOff) + vb00 + f * 1024];              \
      vhi0[f] = *(const bf16x4*)&smem[(vOff) + vb01 + f * 1024];              \
    }                                                                         \
    bf16x8 paf[2][2];                                                         \
    _Pragma("unroll") for (int e = 0; e < 2; ++e) {                           \
      float& m_e = e ? m1 : m0;                                               \
      float& ls_e = e ? ls1 : ls0;                                            \
      float mx = sa[e][0][0];                                                 \
      _Pragma("unroll") for (int sf = 0; sf < 4; ++sf)                        \
        _Pragma("unroll") for (int r = 0; r < 4; ++r)                         \
          mx = fmaxf(mx, sa[e][sf][r]);                                       \
      mx = fmaxf(mx, __shfl_xor(mx, 16));                                     \
      mx = fmaxf(mx, __shfl_xor(mx, 32));                                     \
      if (__any(mx > m_e + THR_LOG2)) {                                       \
        float mn = fmaxf(m_e, mx);                                            \
        float sc = exp2f(m_e - mn);                                           \
        m_e = mn;                                                             \
        ls_e *= sc;                                                           \
        float scr[4];                                                         \
        _Pragma("unroll") for (int r = 0; r < 4; ++r) scr[r] = __shfl(sc, g * 4 + r); \
        _Pragma("unroll") for (int ff = 0; ff < 8; ++ff)                      \
          _Pragma("unroll") for (int r = 0; r < 4; ++r) O[e][ff][r] *= scr[r]; \
      }                                                                       \
      float p[4][4];                                                          \
      float sum = 0.f;                                                        \
      _Pragma("unroll") for (int sf = 0; sf < 4; ++sf)                        \
        _Pragma("unroll") for (int r = 0; r < 4; ++r) {                       \
          float pv = exp2f(sa[e][sf][r] - m_e);                               \
          p[sf][r] = pv;                                                      \
          sum += pv;                                                          \
        }                                                                     \
      sum += __shfl_xor(sum, 16);                                             \
      sum += __shfl_xor(sum, 32);                                             \
      ls_e += sum;                                                            \
      paf[e][0] = (bf16x8){(__bf16)p[0][0], (__bf16)p[0][1], (__bf16)p[0][2], (__bf16)p[0][3], \
                           (__bf16)p[1][0], (__bf16)p[1][1], (__bf16)p[1][2], (__bf16)p[1][3]}; \
      paf[e][1] = (bf16x8){(__bf16)p[2][0], (__bf16)p[2][1], (__bf16)p[2][2], (__bf16)p[2][3], \
                           (__bf16)p[3][0], (__bf16)p[3][1], (__bf16)p[3][2], (__bf16)p[3][3]}; \
    }                                                                         \
    __builtin_amdgcn_s_setprio(1);                                            \
    bf16x4 vlo1[8], vhi1[8];                                                  \
    _Pragma("unroll") for (int f = 0; f < 8; ++f) {                           \
      vlo1[f] = *(const bf16x4*)&smem[(vOff) + vb10 + f * 1024];              \
      vhi1[f] = *(const bf16x4*)&smem[(vOff) + vb11 + f * 1024];              \
    }                                                                         \
    _Pragma("unroll") for (int f = 0; f < 8; ++f) {                           \
      bf16x8 vv = __builtin_shufflevector(vlo0[f], vhi0[f], 0, 1, 2, 3, 4, 5, 6, 7); \
      O[0][f] = mfma16(paf[0][0], vv, O[0][f]);                               \
      O[1][f] = mfma16(paf[1][0], vv, O[1][f]);                               \
    }                                                                         \
    _Pragma("unroll") for (int f = 0; f < 8; ++f) {                           \
      bf16x8 vv = __builtin_shufflevector(vlo1[f], vhi1[f], 0, 1, 2, 3, 4, 5, 6, 7); \
      O[0][f] = mfma16(paf[0][1], vv, O[0][f]);                               \
      O[1][f] = mfma16(paf[1][1], vv, O[1][f]);                               \
    }                                                                         \
    __builtin_amdgcn_s_setprio(0);                                            \
  } while (0)

  STAGE(0, 8192, 0);

#pragma unroll 1
  for (int t = 0; t < 32; t += 2) {
    __syncthreads();  // vmcnt(0): buf0 staged; all waves done with buf1
    STAGE(4096, 16384, (t + 1) * 64);
    TILE(0, 8192);
    __syncthreads();  // buf1 staged; all waves done with buf0
    if (t < 30) STAGE(0, 8192, (t + 2) * 64);
    TILE(4096, 16384);
  }

  // epilogue: redistribute 1/ls from c-layout to (g,r)-layout
  float inv0 = 1.f / ls0, inv1 = 1.f / ls1;
  float i0[4], i1[4];
#pragma unroll
  for (int r = 0; r < 4; ++r) {
    i0[r] = __shfl(inv0, g * 4 + r);
    i1[r] = __shfl(inv1, g * 4 + r);
  }
  float res[8][4];
  float ss[4] = {0.f, 0.f, 0.f, 0.f};
#pragma unroll
  for (int f = 0; f < 8; ++f)
#pragma unroll
    for (int r = 0; r < 4; ++r) {
      float vv = O[0][f][r] * i0[r] - lambda_full * (O[1][f][r] * i1[r]);
      res[f][r] = vv;
      ss[r] += vv * vv;
    }
#pragma unroll
  for (int off = 1; off < 16; off <<= 1)
#pragma unroll
    for (int r = 0; r < 4; ++r) ss[r] += __shfl_xor(ss[r], off);
  float rms[4];
#pragma unroll
  for (int r = 0; r < 4; ++r)
    rms[r] = rsqrtf(ss[r] * (1.0f / 128.0f) + 1e-5f) * ONE_MINUS_LI;
  float w[8];
#pragma unroll
  for (int f = 0; f < 8; ++f) w[f] = subln[f * 16 + c];
#pragma unroll
  for (int f = 0; f < 8; ++f)
#pragma unroll
    for (int r = 0; r < 4; ++r)
      AO[(size_t)(t0 + g * 4 + r) * 2048 + h * 128 + f * 16 + c] = f2b(res[f][r] * rms[r] * w[f]);
}

// ------------------------------------------------------------------------------
extern "C" void kernel_launch(void* const* d_in, const int* in_sizes, int n_in,
                              void* d_out, int out_size, void* d_ws, size_t ws_size,
                              hipStream_t stream) {
  const float* q     = (const float*)d_in[0];
  const float* k     = (const float*)d_in[1];
  const float* v     = (const float*)d_in[2];
  const float* Wq    = (const float*)d_in[3];
  const float* Wk    = (const float*)d_in[4];
  const float* Wv    = (const float*)d_in[5];
  const float* Wout  = (const float*)d_in[6];
  const float* lq1   = (const float*)d_in[7];
  const float* lk1   = (const float*)d_in[8];
  const float* lq2   = (const float*)d_in[9];
  const float* lk2   = (const float*)d_in[10];
  const float* subln = (const float*)d_in[11];
  float* out = (float*)d_out;

  char* ws = (char*)d_ws;
  size_t off = 0;
  auto alloc = [&](size_t bytes) -> void* {
    void* p = ws + off;
    off += (bytes + 255) & ~(size_t)255;
    return p;
  };
  u16* qb  = (u16*)alloc(2048ull * 2048 * 2);
  u16* kb  = (u16*)alloc(2048ull * 2048 * 2);
  u16* vb  = (u16*)alloc(2048ull * 2048 * 2);
  u16* WqT = (u16*)alloc(2048ull * 2048 * 2);
  u16* WkT = (u16*)alloc(1024ull * 2048 * 2);
  u16* WvT = (u16*)alloc(1024ull * 2048 * 2);
  u16* WoT = (u16*)alloc(2048ull * 2048 * 2);
  float* QP = (float*)alloc(2048ull * 2048 * 4);
  float* KP = (float*)alloc(2048ull * 1024 * 4);
  float* VP = (float*)alloc(2048ull * 1024 * 4);
  u16* Qh  = (u16*)alloc(32ull * 2048 * 64 * 2);
  u16* Kh  = (u16*)alloc(16ull * 2048 * 64 * 2);
  u16* Vt  = (u16*)alloc(1024ull * 2048 * 2);
  u16* AO  = (u16*)QP;  // alias: QP dead after rope, AO written later

  // 1. cast inputs to bf16 (one launch)
  cast3_kernel<<<6144, 256, 0, stream>>>(q, k, v, qb, kb, vb);
  // 2. transpose+cast all weights -> [N][K] bf16 (one launch)
  wtrans_kernel<<<dim3(64, 64, 4), 256, 0, stream>>>(Wq, WqT, Wk, WkT, Wv, WvT, Wout, WoT);
  // 3. projections (fused single launch, 512 blocks, XCD-swizzled)
  gemm_qkv_kernel<<<512, 256, 0, stream>>>(qb, WqT, QP, kb, WkT, KP, vb, WvT, VP);
  // 4. RoPE Q+K -> head-major bf16 (one launch; Q pre-scaled by 1/8*log2e)
  rope2_kernel<<<dim3(256, 48), 256, 0, stream>>>(QP, KP, Qh, Kh);
  // 5. V transpose: VP [2048][1024] -> Vt [1024][2048]
  transpose_cast_kernel<<<dim3(32, 64), 256, 0, stream>>>(VP, Vt, 2048, 1024);
  // 6. differential flash attention -> AO bf16 [2048][2048]
  attn_kernel<<<512, 256, 0, stream>>>(Qh, Kh, Vt, AO, lq1, lk1, lq2, lk2, subln);
  // 7. output projection -> f32 d_out
  gemm_one_kernel<<<256, 256, 0, stream>>>(AO, WoT, out);
}

// Round 6
// 166.784 us; speedup vs baseline: 2.3795x; 1.1521x over previous
//
#include <hip/hip_runtime.h>

typedef unsigned short u16;
typedef unsigned int u32;
typedef float f32x4 __attribute__((ext_vector_type(4)));
typedef __bf16 bf16x8 __attribute__((ext_vector_type(8)));
typedef __bf16 bf16x4 __attribute__((ext_vector_type(4)));

#define LAMBDA_INIT_F 0.7836057665316245f
#define ONE_MINUS_LI  0.2163942334683755f
#define THR_LOG2 11.0f
// 0.125 * log2(e): fold softmax base-2 conversion into Q scaling
#define Q_SCALE 0.18033688011112042f

__device__ __forceinline__ u16 f2b(float f) {
  union { float f; u32 u; } x; x.f = f;
  u32 r = x.u + 0x7fffu + ((x.u >> 16) & 1u);
  return (u16)(r >> 16);
}

__device__ __forceinline__ f32x4 mfma16(bf16x8 a, bf16x8 b, f32x4 c) {
  return __builtin_amdgcn_mfma_f32_16x16x32_bf16(a, b, c, 0, 0, 0);
}

__device__ __forceinline__ float fexp2(float x) { return __builtin_amdgcn_exp2f(x); }

// async global->LDS, 16B per lane; LDS dest must be linear in lane order
__device__ __forceinline__ void gll16(const void* gp, void* lp) {
  __builtin_amdgcn_global_load_lds((__attribute__((address_space(1))) void*)(gp),
                                   (__attribute__((address_space(3))) void*)(lp),
                                   16, 0, 0);
}

// ---------------- fused cast f32 -> bf16 for q,k,v (8 elems/thread) -----------
__global__ __launch_bounds__(256) void cast3_kernel(const float* __restrict__ q,
                                                    const float* __restrict__ k,
                                                    const float* __restrict__ v,
                                                    u16* __restrict__ qb,
                                                    u16* __restrict__ kb,
                                                    u16* __restrict__ vb) {
  int bid = blockIdx.x;
  int seg = bid >> 11;
  int i = (bid & 2047) * 256 + threadIdx.x;
  const float* in = seg == 0 ? q : (seg == 1 ? k : v);
  u16* out = seg == 0 ? qb : (seg == 1 ? kb : vb);
  const f32x4* p = (const f32x4*)(in + (size_t)i * 8);
  f32x4 a = p[0], b = p[1];
  union { u16 u[8]; f32x4 v; } o;
#pragma unroll
  for (int j = 0; j < 4; ++j) { o.u[j] = f2b(a[j]); o.u[4 + j] = f2b(b[j]); }
  *(f32x4*)(out + (size_t)i * 8) = o.v;
}

// ------------- tiled transpose+cast: in f32 [R][C] -> out bf16 [C][R] ---------
__device__ __forceinline__ void trans_body(const float* __restrict__ in,
                                           u16* __restrict__ out, int R, int C) {
  __shared__ float tile[32][33];
  int bx = blockIdx.x * 32;  // col base
  int by = blockIdx.y * 32;  // row base
  int tx = threadIdx.x & 31, ty = threadIdx.x >> 5;
#pragma unroll
  for (int i = 0; i < 32; i += 8)
    tile[ty + i][tx] = in[(size_t)(by + ty + i) * C + bx + tx];
  __syncthreads();
#pragma unroll
  for (int i = 0; i < 32; i += 8)
    out[(size_t)(bx + ty + i) * R + by + tx] = f2b(tile[tx][ty + i]);
}

// all 4 weight transposes in one launch (grid.z selects)
__global__ __launch_bounds__(256) void wtrans_kernel(
    const float* __restrict__ Wq, u16* __restrict__ WqT,
    const float* __restrict__ Wk, u16* __restrict__ WkT,
    const float* __restrict__ Wv, u16* __restrict__ WvT,
    const float* __restrict__ Wo, u16* __restrict__ WoT) {
  int z = blockIdx.z;
  const float* in;
  u16* out;
  int C;
  if (z == 0)      { in = Wq; out = WqT; C = 2048; }
  else if (z == 1) { in = Wk; out = WkT; C = 1024; }
  else if (z == 2) { in = Wv; out = WvT; C = 1024; }
  else             { in = Wo; out = WoT; C = 2048; }
  if (blockIdx.x * 32 >= C) return;
  trans_body(in, out, 2048, C);
}

// V transpose with PERMUTED key columns: key = 16jh+4g+r -> p = 8g+4jh+r
// (within each 32-key block) so a PV lane fragment is one contiguous granule.
__global__ __launch_bounds__(256) void vtrans_kernel(const float* __restrict__ in,
                                                     u16* __restrict__ out) {
  __shared__ float tile[32][33];
  int bx = blockIdx.x * 32;  // dv base (C=1024)
  int by = blockIdx.y * 32;  // key base (R=2048)
  int tx = threadIdx.x & 31, ty = threadIdx.x >> 5;
#pragma unroll
  for (int i = 0; i < 32; i += 8)
    tile[ty + i][tx] = in[(size_t)(by + ty + i) * 1024 + bx + tx];
  __syncthreads();
  int ptx = 8 * ((tx >> 2) & 3) + 4 * (tx >> 4) + (tx & 3);
#pragma unroll
  for (int i = 0; i < 32; i += 8)
    out[(size_t)(bx + ty + i) * 2048 + by + ptx] = f2b(tile[tx][ty + i]);
}

// ---------------- fused RoPE for Q and K, f32 [T][Hh*64] -> bf16 [Hh][T][64] --
__global__ __launch_bounds__(256) void rope2_kernel(const float* __restrict__ QP,
                                                    const float* __restrict__ KP,
                                                    u16* __restrict__ Qh,
                                                    u16* __restrict__ Kh) {
  int hh = blockIdx.y;  // 0..47: 0-31 -> Q half-heads, 32-47 -> K half-heads
  int idx = blockIdx.x * 256 + threadIdx.x;
  int j = idx & 31;
  int t = idx >> 5;
  const float* in;
  u16* out;
  int Hh, hl;
  float scale;
  if (hh < 32) { in = QP; out = Qh; Hh = 32; hl = hh; scale = Q_SCALE; }
  else         { in = KP; out = Kh; Hh = 16; hl = hh - 32; scale = 1.0f; }
  const float* src = in + (size_t)t * (Hh * 64) + hl * 64 + 2 * j;
  float x1 = src[0], x2 = src[1];
  float theta = (float)j * (1.0f / 32.0f);
  float denom = expf(theta * 9.210340371976184f);  // 10000^theta
  float invf = 1.0f / (denom + 1e-8f);
  float ang = (float)t * invf;
  float s = sinf(ang), c = cosf(ang);
  float o1 = (x1 * c - x2 * s) * scale;
  float o2 = (x1 * s + x2 * c) * scale;
  u32 pk = (u32)f2b(o1) | ((u32)f2b(o2) << 16);
  *(u32*)(out + ((size_t)hl * 2048 + t) * 64 + 2 * j) = pk;
}

// ------- GEMM body: 128x64 tile, BK=64: C[M][N] f32 = A[M][K] * Bt[N][K] ------
__device__ __forceinline__ void gemm_body64(u16* As, u16* Bs,
                                            const u16* __restrict__ A,
                                            const u16* __restrict__ Bt,
                                            float* __restrict__ C,
                                            int N, int K, int bx, int by) {
  const int tid = threadIdx.x;
  const int lane = tid & 63;
  const int wave = tid >> 6;
  const int m0 = by * 128;
  const int n0 = bx * 64;
  const int wm = (wave >> 1) * 64;
  const int wn = (wave & 1) * 32;
  const int g = lane >> 4, c = lane & 15;

  f32x4 acc[4][2];
#pragma unroll
  for (int i = 0; i < 4; ++i)
#pragma unroll
    for (int j = 0; j < 2; ++j) acc[i][j] = (f32x4){0.f, 0.f, 0.f, 0.f};

  for (int k0 = 0; k0 < K; k0 += 64) {
    __syncthreads();
#pragma unroll
    for (int it = 0; it < 4; ++it) {
      int gi = it * 256 + tid;
      int R = gi >> 3;
      int lg = (gi & 7) ^ (R & 7);
      gll16(A + (size_t)(m0 + R) * K + k0 + lg * 8, As + gi * 8);
    }
#pragma unroll
    for (int it = 0; it < 2; ++it) {
      int gi = it * 256 + tid;
      int R = gi >> 3;
      int lg = (gi & 7) ^ (R & 7);
      gll16(Bt + (size_t)(n0 + R) * K + k0 + lg * 8, Bs + gi * 8);
    }
    __syncthreads();
#pragma unroll
    for (int kk = 0; kk < 2; ++kk) {
      bf16x8 af[4], bf[2];
      int ph = ((kk * 4 + g) ^ (c & 7)) * 8;
#pragma unroll
      for (int i = 0; i < 4; ++i) af[i] = *(const bf16x8*)&As[(wm + i * 16 + c) * 64 + ph];
#pragma unroll
      for (int j = 0; j < 2; ++j) bf[j] = *(const bf16x8*)&Bs[(wn + j * 16 + c) * 64 + ph];
#pragma unroll
      for (int i = 0; i < 4; ++i)
#pragma unroll
        for (int j = 0; j < 2; ++j) acc[i][j] = mfma16(af[i], bf[j], acc[i][j]);
    }
  }
#pragma unroll
  for (int i = 0; i < 4; ++i)
#pragma unroll
    for (int j = 0; j < 2; ++j) {
      int mrow = m0 + wm + i * 16 + g * 4;
      int ncol = n0 + wn + j * 16 + c;
#pragma unroll
      for (int r = 0; r < 4; ++r) C[(size_t)(mrow + r) * N + ncol] = acc[i][j][r];
    }
}

// fused q/k/v projections: 512 + 256 + 256 = 1024 blocks (4/CU)
__global__ __launch_bounds__(256, 4) void gemm_qkv_kernel(
    const u16* __restrict__ qb, const u16* __restrict__ WqT, float* __restrict__ QP,
    const u16* __restrict__ kb, const u16* __restrict__ WkT, float* __restrict__ KP,
    const u16* __restrict__ vb, const u16* __restrict__ WvT, float* __restrict__ VP) {
  __shared__ u16 As[128 * 64];
  __shared__ u16 Bs[64 * 64];
  // XCD-aware swizzle: 1024 blocks, 128 consecutive work-ids per XCD
  int bid = ((blockIdx.x & 7) << 7) | (blockIdx.x >> 3);
  if (bid < 512) {
    gemm_body64(As, Bs, qb, WqT, QP, 2048, 2048, bid & 31, bid >> 5);
  } else if (bid < 768) {
    int t = bid - 512;
    gemm_body64(As, Bs, kb, WkT, KP, 1024, 2048, t & 15, t >> 4);
  } else {
    int t = bid - 768;
    gemm_body64(As, Bs, vb, WvT, VP, 1024, 2048, t & 15, t >> 4);
  }
}

__global__ __launch_bounds__(256, 2) void gemm_one_kernel(const u16* __restrict__ A,
                                                          const u16* __restrict__ Bt,
                                                          float* __restrict__ C) {
  __shared__ u16 As[128 * 64];
  __shared__ u16 Bs[64 * 64];
  int bid = ((blockIdx.x & 7) << 6) | (blockIdx.x >> 3);  // 512 blocks
  gemm_body64(As, Bs, A, Bt, C, 2048, 2048, bid & 31, bid >> 5);
}

// ---------------- fused differential flash attention --------------------------
// 8-wave blocks (512 thr), 256 blocks: block = 1 head x 128 q-rows; K/V staged
// once per 128 rows (staging traffic & barrier events halved vs 4-wave).
// Permuted Vt global layout -> PV fragment = ONE ds_read_b128 at kb0 / kb0^32
// (same constants as K reads). All softmax exp via raw v_exp_f32.
__global__ __launch_bounds__(512, 2) void attn_kernel(const u16* __restrict__ Qb,
                                                      const u16* __restrict__ Kb,
                                                      const u16* __restrict__ Vt,
                                                      u16* __restrict__ AO,
                                                      const float* __restrict__ lq1,
                                                      const float* __restrict__ lk1,
                                                      const float* __restrict__ lq2,
                                                      const float* __restrict__ lk2,
                                                      const float* __restrict__ subln) {
  // XCD swizzle: 32 consecutive work-ids (2 heads) per XCD's L2
  const int b = ((blockIdx.x & 7) << 5) | (blockIdx.x >> 3);
  const int h = b >> 4;
  const int tid = threadIdx.x;
  const int wave = tid >> 6;
  const int lane = tid & 63;
  const int t0 = ((b & 15) * 8 + wave) * 16;
  const int g = lane >> 4, c = lane & 15;
  const int c7 = c & 7;

  __shared__ u16 smem[24576];  // 48KB: K0@0 K1@4096 V0@8192 V1@16384

  const u16* Kh = Kb + (size_t)h * 2048 * 64;
  const u16* Vh = Vt + (size_t)(h >> 1) * 128 * 2048;

  // lambda (wave-parallel)
  float myl1 = lq1[lane] * lk1[lane];
  float myl2 = lq2[lane] * lk2[lane];
#pragma unroll
  for (int off = 32; off; off >>= 1) {
    myl1 += __shfl_xor(myl1, off);
    myl2 += __shfl_xor(myl2, off);
  }
  const float lambda_full = expf(myl1) - expf(myl2) + LAMBDA_INIT_F;

  // Q fragments (B-operand: col = q-row = c, natural d-slots)
  bf16x8 qf[2][2];
#pragma unroll
  for (int e = 0; e < 2; ++e)
#pragma unroll
    for (int d = 0; d < 2; ++d)
      qf[e][d] = *(const bf16x8*)(Qb + ((size_t)(2 * h + e) * 2048 + t0 + c) * 64 + d * 32 + g * 8);

  // loop-invariant LDS read bases (u16-elem units); shared by K and V reads
  const int kb0 = c * 64 + ((g ^ c7) * 8);
  const int kb1 = kb0 ^ 32;

  // per-thread stage source bases (granule-XOR pre-swizzled)
  const u16* ksrc0;
  const u16* vsrc0;
  const u16* vsrc1;
  { int gi = tid;       int R = gi >> 3; ksrc0 = Kh + R * 64 + ((gi & 7) ^ (R & 7)) * 8; }
  { int gi = tid;       int R = gi >> 3; vsrc0 = Vh + (size_t)R * 2048 + ((gi & 7) ^ (R & 7)) * 8; }
  { int gi = 512 + tid; int R = gi >> 3; vsrc1 = Vh + (size_t)R * 2048 + ((gi & 7) ^ (R & 7)) * 8; }

  f32x4 O[2][8];
#pragma unroll
  for (int e = 0; e < 2; ++e)
#pragma unroll
    for (int f = 0; f < 8; ++f) O[e][f] = (f32x4){0.f, 0.f, 0.f, 0.f};
  float m0 = -1e30f, m1 = -1e30f, ls0 = 0.f, ls1 = 0.f;

#define STAGE(kOff, vOff, s0)                                   \
  do {                                                          \
    gll16(ksrc0 + (size_t)(s0) * 64, smem + (kOff) + tid * 8);  \
    gll16(vsrc0 + (s0), smem + (vOff) + tid * 8);               \
    gll16(vsrc1 + (s0), smem + (vOff) + 4096 + tid * 8);        \
  } while (0)

#define TILE(kOff, vOff)                                                      \
  do {                                                                        \
    bf16x8 kf[4][2];                                                          \
    _Pragma("unroll") for (int sf = 0; sf < 4; ++sf) {                        \
      kf[sf][0] = *(const bf16x8*)&smem[(kOff) + kb0 + sf * 1024];            \
      kf[sf][1] = *(const bf16x8*)&smem[(kOff) + kb1 + sf * 1024];            \
    }                                                                         \
    f32x4 sa[2][4];                                                           \
    _Pragma("unroll") for (int e = 0; e < 2; ++e)                             \
      _Pragma("unroll") for (int sf = 0; sf < 4; ++sf) {                      \
        f32x4 z = (f32x4){0.f, 0.f, 0.f, 0.f};                                \
        z = mfma16(kf[sf][0], qf[e][0], z);                                   \
        z = mfma16(kf[sf][1], qf[e][1], z);                                   \
        sa[e][sf] = z;                                                        \
      }                                                                       \
    bf16x8 vv0[8];                                                            \
    _Pragma("unroll") for (int f = 0; f < 8; ++f)                             \
      vv0[f] = *(const bf16x8*)&smem[(vOff) + kb0 + f * 1024];                \
    bf16x8 paf[2][2];                                                         \
    _Pragma("unroll") for (int e = 0; e < 2; ++e) {                           \
      float& m_e = e ? m1 : m0;                                               \
      float& ls_e = e ? ls1 : ls0;                                            \
      float mx = sa[e][0][0];                                                 \
      _Pragma("unroll") for (int sf = 0; sf < 4; ++sf)                        \
        _Pragma("unroll") for (int r = 0; r < 4; ++r)                         \
          mx = fmaxf(mx, sa[e][sf][r]);                                       \
      mx = fmaxf(mx, __shfl_xor(mx, 16));                                     \
      mx = fmaxf(mx, __shfl_xor(mx, 32));                                     \
      if (__any(mx > m_e + THR_LOG2)) {                                       \
        float mn = fmaxf(m_e, mx);                                            \
        float sc = fexp2(m_e - mn);                                           \
        m_e = mn;                                                             \
        ls_e *= sc;                                                           \
        float scr[4];                                                         \
        _Pragma("unroll") for (int r = 0; r < 4; ++r) scr[r] = __shfl(sc, g * 4 + r); \
        _Pragma("unroll") for (int ff = 0; ff < 8; ++ff)                      \
          _Pragma("unroll") for (int r = 0; r < 4; ++r) O[e][ff][r] *= scr[r]; \
      }                                                                       \
      float p[4][4];                                                          \
      float sum = 0.f;                                                        \
      _Pragma("unroll") for (int sf = 0; sf < 4; ++sf)                        \
        _Pragma("unroll") for (int r = 0; r < 4; ++r) {                       \
          float pv = fexp2(sa[e][sf][r] - m_e);                               \
          p[sf][r] = pv;                                                      \
          sum += pv;                                                          \
        }                                                                     \
      sum += __shfl_xor(sum, 16);                                             \
      sum += __shfl_xor(sum, 32);                                             \
      ls_e += sum;                                                            \
      paf[e][0] = (bf16x8){(__bf16)p[0][0], (__bf16)p[0][1], (__bf16)p[0][2], (__bf16)p[0][3], \
                           (__bf16)p[1][0], (__bf16)p[1][1], (__bf16)p[1][2], (__bf16)p[1][3]}; \
      paf[e][1] = (bf16x8){(__bf16)p[2][0], (__bf16)p[2][1], (__bf16)p[2][2], (__bf16)p[2][3], \
                           (__bf16)p[3][0], (__bf16)p[3][1], (__bf16)p[3][2], (__bf16)p[3][3]}; \
    }                                                                         \
    __builtin_amdgcn_s_setprio(1);                                            \
    bf16x8 vv1[8];                                                            \
    _Pragma("unroll") for (int f = 0; f < 8; ++f)                             \
      vv1[f] = *(const bf16x8*)&smem[(vOff) + kb1 + f * 1024];                \
    _Pragma("unroll") for (int f = 0; f < 8; ++f) {                           \
      O[0][f] = mfma16(paf[0][0], vv0[f], O[0][f]);                           \
      O[1][f] = mfma16(paf[1][0], vv0[f], O[1][f]);                           \
    }                                                                         \
    _Pragma("unroll") for (int f = 0; f < 8; ++f) {                           \
      O[0][f] = mfma16(paf[0][1], vv1[f], O[0][f]);                           \
      O[1][f] = mfma16(paf[1][1], vv1[f], O[1][f]);                           \
    }                                                                         \
    __builtin_amdgcn_s_setprio(0);                                            \
  } while (0)

  STAGE(0, 8192, 0);

#pragma unroll 1
  for (int t = 0; t < 32; t += 2) {
    __syncthreads();  // vmcnt(0): buf0 staged; all waves done with buf1
    STAGE(4096, 16384, (t + 1) * 64);
    TILE(0, 8192);
    __syncthreads();  // buf1 staged; all waves done with buf0
    if (t < 30) STAGE(0, 8192, (t + 2) * 64);
    TILE(4096, 16384);
  }

  // epilogue: redistribute 1/ls from c-layout to (g,r)-layout
  float inv0 = 1.f / ls0, inv1 = 1.f / ls1;
  float i0[4], i1[4];
#pragma unroll
  for (int r = 0; r < 4; ++r) {
    i0[r] = __shfl(inv0, g * 4 + r);
    i1[r] = __shfl(inv1, g * 4 + r);
  }
  float res[8][4];
  float ss[4] = {0.f, 0.f, 0.f, 0.f};
#pragma unroll
  for (int f = 0; f < 8; ++f)
#pragma unroll
    for (int r = 0; r < 4; ++r) {
      float vv = O[0][f][r] * i0[r] - lambda_full * (O[1][f][r] * i1[r]);
      res[f][r] = vv;
      ss[r] += vv * vv;
    }
#pragma unroll
  for (int off = 1; off < 16; off <<= 1)
#pragma unroll
    for (int r = 0; r < 4; ++r) ss[r] += __shfl_xor(ss[r], off);
  float rms[4];
#pragma unroll
  for (int r = 0; r < 4; ++r)
    rms[r] = rsqrtf(ss[r] * (1.0f / 128.0f) + 1e-5f) * ONE_MINUS_LI;
  float w[8];
#pragma unroll
  for (int f = 0; f < 8; ++f) w[f] = subln[f * 16 + c];
#pragma unroll
  for (int f = 0; f < 8; ++f)
#pragma unroll
    for (int r = 0; r < 4; ++r)
      AO[(size_t)(t0 + g * 4 + r) * 2048 + h * 128 + f * 16 + c] = f2b(res[f][r] * rms[r] * w[f]);
}

// ------------------------------------------------------------------------------
extern "C" void kernel_launch(void* const* d_in, const int* in_sizes, int n_in,
                              void* d_out, int out_size, void* d_ws, size_t ws_size,
                              hipStream_t stream) {
  const float* q     = (const float*)d_in[0];
  const float* k     = (const float*)d_in[1];
  const float* v     = (const float*)d_in[2];
  const float* Wq    = (const float*)d_in[3];
  const float* Wk    = (const float*)d_in[4];
  const float* Wv    = (const float*)d_in[5];
  const float* Wout  = (const float*)d_in[6];
  const float* lq1   = (const float*)d_in[7];
  const float* lk1   = (const float*)d_in[8];
  const float* lq2   = (const float*)d_in[9];
  const float* lk2   = (const float*)d_in[10];
  const float* subln = (const float*)d_in[11];
  float* out = (float*)d_out;

  char* ws = (char*)d_ws;
  size_t off = 0;
  auto alloc = [&](size_t bytes) -> void* {
    void* p = ws + off;
    off += (bytes + 255) & ~(size_t)255;
    return p;
  };
  u16* qb  = (u16*)alloc(2048ull * 2048 * 2);
  u16* kb  = (u16*)alloc(2048ull * 2048 * 2);
  u16* vb  = (u16*)alloc(2048ull * 2048 * 2);
  u16* WqT = (u16*)alloc(2048ull * 2048 * 2);
  u16* WkT = (u16*)alloc(1024ull * 2048 * 2);
  u16* WvT = (u16*)alloc(1024ull * 2048 * 2);
  u16* WoT = (u16*)alloc(2048ull * 2048 * 2);
  float* QP = (float*)alloc(2048ull * 2048 * 4);
  float* KP = (float*)alloc(2048ull * 1024 * 4);
  float* VP = (float*)alloc(2048ull * 1024 * 4);
  u16* Qh  = (u16*)alloc(32ull * 2048 * 64 * 2);
  u16* Kh  = (u16*)alloc(16ull * 2048 * 64 * 2);
  u16* Vt  = (u16*)alloc(1024ull * 2048 * 2);
  u16* AO  = (u16*)QP;  // alias: QP dead after rope, AO written later

  // 1. cast inputs to bf16 (one launch)
  cast3_kernel<<<6144, 256, 0, stream>>>(q, k, v, qb, kb, vb);
  // 2. transpose+cast all weights -> [N][K] bf16 (one launch)
  wtrans_kernel<<<dim3(64, 64, 4), 256, 0, stream>>>(Wq, WqT, Wk, WkT, Wv, WvT, Wout, WoT);
  // 3. projections (fused single launch, 1024 blocks, 4/CU, XCD-swizzled)
  gemm_qkv_kernel<<<1024, 256, 0, stream>>>(qb, WqT, QP, kb, WkT, KP, vb, WvT, VP);
  // 4. RoPE Q+K -> head-major bf16 (one launch; Q pre-scaled by 1/8*log2e)
  rope2_kernel<<<dim3(256, 48), 256, 0, stream>>>(QP, KP, Qh, Kh);
  // 5. V transpose with permuted key columns: VP [2048][1024] -> Vt' [1024][2048]
  vtrans_kernel<<<dim3(32, 64), 256, 0, stream>>>(VP, Vt);
  // 6. differential flash attention -> AO bf16 [2048][2048]
  attn_kernel<<<256, 512, 0, stream>>>(Qh, Kh, Vt, AO, lq1, lk1, lq2, lk2, subln);
  // 7. output projection -> f32 d_out
  gemm_one_kernel<<<512, 256, 0, stream>>>(AO, WoT, out);
}

// Round 7
// 156.249 us; speedup vs baseline: 2.5399x; 1.0674x over previous
//
#include <hip/hip_runtime.h>

typedef unsigned short u16;
typedef unsigned int u32;
typedef float f32x4 __attribute__((ext_vector_type(4)));
typedef float f32x2 __attribute__((ext_vector_type(2)));
typedef unsigned int u32x2 __attribute__((ext_vector_type(2)));
typedef __bf16 bf16x8 __attribute__((ext_vector_type(8)));
typedef __bf16 bf16x4 __attribute__((ext_vector_type(4)));

#define LAMBDA_INIT_F 0.7836057665316245f
#define ONE_MINUS_LI  0.2163942334683755f
#define THR_LOG2 11.0f
// 0.125 * log2(e): fold softmax base-2 conversion into Q scaling
#define Q_SCALE 0.18033688011112042f

__device__ __forceinline__ u16 f2b(float f) {
  union { float f; u32 u; } x; x.f = f;
  u32 r = x.u + 0x7fffu + ((x.u >> 16) & 1u);
  return (u16)(r >> 16);
}

__device__ __forceinline__ f32x4 mfma16(bf16x8 a, bf16x8 b, f32x4 c) {
  return __builtin_amdgcn_mfma_f32_16x16x32_bf16(a, b, c, 0, 0, 0);
}

__device__ __forceinline__ float fexp2(float x) { return __builtin_amdgcn_exp2f(x); }

// async global->LDS, 16B per lane; LDS dest must be linear in lane order
__device__ __forceinline__ void gll16(const void* gp, void* lp) {
  __builtin_amdgcn_global_load_lds((__attribute__((address_space(1))) void*)(gp),
                                   (__attribute__((address_space(3))) void*)(lp),
                                   16, 0, 0);
}

// ------ fused cast f32 -> bf16 for q,k,v (8 elems/thread) + rope table --------
__global__ __launch_bounds__(256) void cast3_kernel(const float* __restrict__ q,
                                                    const float* __restrict__ k,
                                                    const float* __restrict__ v,
                                                    u16* __restrict__ qb,
                                                    u16* __restrict__ kb,
                                                    u16* __restrict__ vb,
                                                    f32x2* __restrict__ tbl) {
  int bid = blockIdx.x;
  if (bid >= 6144) {
    // cos/sin table: idx = t*32 + j, 2048*32 entries
    int idx = (bid - 6144) * 256 + threadIdx.x;
    int t = idx >> 5, j = idx & 31;
    float theta = (float)j * (1.0f / 32.0f);
    float denom = expf(theta * 9.210340371976184f);  // 10000^theta
    float invf = 1.0f / (denom + 1e-8f);
    float ang = (float)t * invf;
    tbl[idx] = (f32x2){cosf(ang), sinf(ang)};
    return;
  }
  int seg = bid >> 11;
  int i = (bid & 2047) * 256 + threadIdx.x;
  const float* in = seg == 0 ? q : (seg == 1 ? k : v);
  u16* out = seg == 0 ? qb : (seg == 1 ? kb : vb);
  const f32x4* p = (const f32x4*)(in + (size_t)i * 8);
  f32x4 a = p[0], b = p[1];
  union { u16 u[8]; f32x4 v; } o;
#pragma unroll
  for (int j = 0; j < 4; ++j) { o.u[j] = f2b(a[j]); o.u[4 + j] = f2b(b[j]); }
  *(f32x4*)(out + (size_t)i * 8) = o.v;
}

// ------------- tiled transpose+cast: in f32 [R][C] -> out bf16 [C][R] ---------
__device__ __forceinline__ void trans_body(const float* __restrict__ in,
                                           u16* __restrict__ out, int R, int C) {
  __shared__ float tile[32][33];
  int bx = blockIdx.x * 32;  // col base
  int by = blockIdx.y * 32;  // row base
  int tx = threadIdx.x & 31, ty = threadIdx.x >> 5;
#pragma unroll
  for (int i = 0; i < 32; i += 8)
    tile[ty + i][tx] = in[(size_t)(by + ty + i) * C + bx + tx];
  __syncthreads();
#pragma unroll
  for (int i = 0; i < 32; i += 8)
    out[(size_t)(bx + ty + i) * R + by + tx] = f2b(tile[tx][ty + i]);
}

// all 4 weight transposes in one launch (grid.z selects)
__global__ __launch_bounds__(256) void wtrans_kernel(
    const float* __restrict__ Wq, u16* __restrict__ WqT,
    const float* __restrict__ Wk, u16* __restrict__ WkT,
    const float* __restrict__ Wv, u16* __restrict__ WvT,
    const float* __restrict__ Wo, u16* __restrict__ WoT) {
  int z = blockIdx.z;
  const float* in;
  u16* out;
  int C;
  if (z == 0)      { in = Wq; out = WqT; C = 2048; }
  else if (z == 1) { in = Wk; out = WkT; C = 1024; }
  else if (z == 2) { in = Wv; out = WvT; C = 1024; }
  else             { in = Wo; out = WoT; C = 2048; }
  if (blockIdx.x * 32 >= C) return;
  trans_body(in, out, 2048, C);
}

// ---------------- GEMM body: 128x128 tile, BK=64, fused epilogues -------------
// MODE 0: plain f32 C[M][N]
// MODE 1: RoPE (interleaved pairs via shfl_xor(1), table cos/sin) -> bf16
//         head-major Oh[ncol>>6][t][64]; even lanes store packed u32 pairs.
// MODE 2: V permuted transpose -> bf16 Vt[dv][2048]; within each 32-key block
//         position p = 8g + 4(i&1) + r (r-contiguous -> one 8B store per quad).
template <int MODE>
__device__ __forceinline__ void gemm_body(u16* As, u16* Bs,
                                          const u16* __restrict__ A,
                                          const u16* __restrict__ Bt,
                                          void* __restrict__ Cout,
                                          const f32x2* __restrict__ tbl,
                                          float scale,
                                          int N, int K, int bx, int by) {
  const int tid = threadIdx.x;
  const int lane = tid & 63;
  const int wave = tid >> 6;
  const int m0 = by * 128;
  const int n0 = bx * 128;
  const int wm = (wave >> 1) * 64;
  const int wn = (wave & 1) * 64;
  const int g = lane >> 4, c = lane & 15;

  f32x4 acc[4][4];
#pragma unroll
  for (int i = 0; i < 4; ++i)
#pragma unroll
    for (int j = 0; j < 4; ++j) acc[i][j] = (f32x4){0.f, 0.f, 0.f, 0.f};

  for (int k0 = 0; k0 < K; k0 += 64) {
    __syncthreads();
#pragma unroll
    for (int it = 0; it < 4; ++it) {
      int gi = it * 256 + tid;
      int R = gi >> 3;
      int lg = (gi & 7) ^ (R & 7);
      gll16(A + (size_t)(m0 + R) * K + k0 + lg * 8, As + gi * 8);
      gll16(Bt + (size_t)(n0 + R) * K + k0 + lg * 8, Bs + gi * 8);
    }
    __syncthreads();
#pragma unroll
    for (int kk = 0; kk < 2; ++kk) {
      bf16x8 af[4], bf[4];
#pragma unroll
      for (int i = 0; i < 4; ++i) {
        int ph = ((kk * 4 + g) ^ (c & 7)) * 8;
        af[i] = *(const bf16x8*)&As[(wm + i * 16 + c) * 64 + ph];
        bf[i] = *(const bf16x8*)&Bs[(wn + i * 16 + c) * 64 + ph];
      }
#pragma unroll
      for (int i = 0; i < 4; ++i)
#pragma unroll
        for (int j = 0; j < 4; ++j) acc[i][j] = mfma16(af[i], bf[j], acc[i][j]);
    }
  }

  if constexpr (MODE == 0) {
    float* C = (float*)Cout;
#pragma unroll
    for (int i = 0; i < 4; ++i)
#pragma unroll
      for (int j = 0; j < 4; ++j) {
        int mrow = m0 + wm + i * 16 + g * 4;
        int ncol = n0 + wn + j * 16 + c;
#pragma unroll
        for (int r = 0; r < 4; ++r) C[(size_t)(mrow + r) * N + ncol] = acc[i][j][r];
      }
  } else if constexpr (MODE == 1) {
    u16* Oh = (u16*)Cout;
    const bool even = (c & 1) == 0;
#pragma unroll
    for (int i = 0; i < 4; ++i)
#pragma unroll
      for (int j = 0; j < 4; ++j) {
        int mrow = m0 + wm + i * 16 + g * 4;
        int ncol = n0 + wn + j * 16 + c;
        int hh = ncol >> 6;
        int d = ncol & 63;
        int jd = d >> 1;
        f32x4 own = acc[i][j];
        f32x4 part;
#pragma unroll
        for (int r = 0; r < 4; ++r) part[r] = __shfl_xor(own[r], 1);
        if (even) {
#pragma unroll
          for (int r = 0; r < 4; ++r) {
            f32x2 cs = tbl[(mrow + r) * 32 + jd];
            float o1 = (own[r] * cs[0] - part[r] * cs[1]) * scale;
            float o2 = (own[r] * cs[1] + part[r] * cs[0]) * scale;
            u32 pk = (u32)f2b(o1) | ((u32)f2b(o2) << 16);
            *(u32*)&Oh[((size_t)hh * 2048 + mrow + r) * 64 + d] = pk;
          }
        }
      }
  } else {
    u16* Vt = (u16*)Cout;
#pragma unroll
    for (int i = 0; i < 4; ++i)
#pragma unroll
      for (int j = 0; j < 4; ++j) {
        int ncol = n0 + wn + j * 16 + c;              // dv
        int tblk = (m0 + wm + i * 16) >> 5;           // 32-key block
        int p0 = 8 * g + 4 * (i & 1);                 // permuted base, +r contiguous
        u32x2 pk;
        pk[0] = (u32)f2b(acc[i][j][0]) | ((u32)f2b(acc[i][j][1]) << 16);
        pk[1] = (u32)f2b(acc[i][j][2]) | ((u32)f2b(acc[i][j][3]) << 16);
        *(u32x2*)&Vt[(size_t)ncol * 2048 + tblk * 32 + p0] = pk;
      }
  }
}

// fused q/k/v projections + RoPE + V-transpose epilogues: 512 blocks (2/CU)
__global__ __launch_bounds__(256, 2) void gemm_qkv_kernel(
    const u16* __restrict__ qb, const u16* __restrict__ WqT, u16* __restrict__ Qh,
    const u16* __restrict__ kb, const u16* __restrict__ WkT, u16* __restrict__ Kh,
    const u16* __restrict__ vb, const u16* __restrict__ WvT, u16* __restrict__ Vt,
    const f32x2* __restrict__ tbl) {
  __shared__ u16 As[128 * 64];
  __shared__ u16 Bs[128 * 64];
  // XCD-aware swizzle: 512 blocks, 64 consecutive work-ids per XCD
  int bid = ((blockIdx.x & 7) << 6) | (blockIdx.x >> 3);
  if (bid < 256) {
    gemm_body<1>(As, Bs, qb, WqT, Qh, tbl, Q_SCALE, 2048, 2048, bid & 15, bid >> 4);
  } else if (bid < 384) {
    int t = bid - 256;
    gemm_body<1>(As, Bs, kb, WkT, Kh, tbl, 1.0f, 1024, 2048, t & 7, t >> 3);
  } else {
    int t = bid - 384;
    gemm_body<2>(As, Bs, vb, WvT, Vt, tbl, 1.0f, 1024, 2048, t & 7, t >> 3);
  }
}

__global__ __launch_bounds__(256, 2) void gemm_one_kernel(const u16* __restrict__ A,
                                                          const u16* __restrict__ Bt,
                                                          float* __restrict__ C) {
  __shared__ u16 As[128 * 64];
  __shared__ u16 Bs[128 * 64];
  int bid = ((blockIdx.x & 7) << 5) | (blockIdx.x >> 3);  // 256 blocks
  gemm_body<0>(As, Bs, A, Bt, C, nullptr, 1.0f, 2048, 2048, bid & 15, bid >> 4);
}

// ---------------- fused differential flash attention (R6, unchanged) ----------
__global__ __launch_bounds__(512, 2) void attn_kernel(const u16* __restrict__ Qb,
                                                      const u16* __restrict__ Kb,
                                                      const u16* __restrict__ Vt,
                                                      u16* __restrict__ AO,
                                                      const float* __restrict__ lq1,
                                                      const float* __restrict__ lk1,
                                                      const float* __restrict__ lq2,
                                                      const float* __restrict__ lk2,
                                                      const float* __restrict__ subln) {
  // XCD swizzle: 32 consecutive work-ids (2 heads) per XCD's L2
  const int b = ((blockIdx.x & 7) << 5) | (blockIdx.x >> 3);
  const int h = b >> 4;
  const int tid = threadIdx.x;
  const int wave = tid >> 6;
  const int lane = tid & 63;
  const int t0 = ((b & 15) * 8 + wave) * 16;
  const int g = lane >> 4, c = lane & 15;
  const int c7 = c & 7;

  __shared__ u16 smem[24576];  // 48KB: K0@0 K1@4096 V0@8192 V1@16384

  const u16* Kh = Kb + (size_t)h * 2048 * 64;
  const u16* Vh = Vt + (size_t)(h >> 1) * 128 * 2048;

  // lambda (wave-parallel)
  float myl1 = lq1[lane] * lk1[lane];
  float myl2 = lq2[lane] * lk2[lane];
#pragma unroll
  for (int off = 32; off; off >>= 1) {
    myl1 += __shfl_xor(myl1, off);
    myl2 += __shfl_xor(myl2, off);
  }
  const float lambda_full = expf(myl1) - expf(myl2) + LAMBDA_INIT_F;

  // Q fragments (B-operand: col = q-row = c, natural d-slots)
  bf16x8 qf[2][2];
#pragma unroll
  for (int e = 0; e < 2; ++e)
#pragma unroll
    for (int d = 0; d < 2; ++d)
      qf[e][d] = *(const bf16x8*)(Qb + ((size_t)(2 * h + e) * 2048 + t0 + c) * 64 + d * 32 + g * 8);

  // loop-invariant LDS read bases (u16-elem units); shared by K and V reads
  const int kb0 = c * 64 + ((g ^ c7) * 8);
  const int kb1 = kb0 ^ 32;

  // per-thread stage source bases (granule-XOR pre-swizzled)
  const u16* ksrc0;
  const u16* vsrc0;
  const u16* vsrc1;
  { int gi = tid;       int R = gi >> 3; ksrc0 = Kh + R * 64 + ((gi & 7) ^ (R & 7)) * 8; }
  { int gi = tid;       int R = gi >> 3; vsrc0 = Vh + (size_t)R * 2048 + ((gi & 7) ^ (R & 7)) * 8; }
  { int gi = 512 + tid; int R = gi >> 3; vsrc1 = Vh + (size_t)R * 2048 + ((gi & 7) ^ (R & 7)) * 8; }

  f32x4 O[2][8];
#pragma unroll
  for (int e = 0; e < 2; ++e)
#pragma unroll
    for (int f = 0; f < 8; ++f) O[e][f] = (f32x4){0.f, 0.f, 0.f, 0.f};
  float m0 = -1e30f, m1 = -1e30f, ls0 = 0.f, ls1 = 0.f;

#define STAGE(kOff, vOff, s0)                                   \
  do {                                                          \
    gll16(ksrc0 + (size_t)(s0) * 64, smem + (kOff) + tid * 8);  \
    gll16(vsrc0 + (s0), smem + (vOff) + tid * 8);               \
    gll16(vsrc1 + (s0), smem + (vOff) + 4096 + tid * 8);        \
  } while (0)

#define TILE(kOff, vOff)                                                      \
  do {                                                                        \
    bf16x8 kf[4][2];                                                          \
    _Pragma("unroll") for (int sf = 0; sf < 4; ++sf) {                        \
      kf[sf][0] = *(const bf16x8*)&smem[(kOff) + kb0 + sf * 1024];            \
      kf[sf][1] = *(const bf16x8*)&smem[(kOff) + kb1 + sf * 1024];            \
    }                                                                         \
    f32x4 sa[2][4];                                                           \
    _Pragma("unroll") for (int e = 0; e < 2; ++e)                             \
      _Pragma("unroll") for (int sf = 0; sf < 4; ++sf) {                      \
        f32x4 z = (f32x4){0.f, 0.f, 0.f, 0.f};                                \
        z = mfma16(kf[sf][0], qf[e][0], z);                                   \
        z = mfma16(kf[sf][1], qf[e][1], z);                                   \
        sa[e][sf] = z;                                                        \
      }                                                                       \
    bf16x8 vv0[8];                                                            \
    _Pragma("unroll") for (int f = 0; f < 8; ++f)                             \
      vv0[f] = *(const bf16x8*)&smem[(vOff) + kb0 + f * 1024];                \
    bf16x8 paf[2][2];                                                         \
    _Pragma("unroll") for (int e = 0; e < 2; ++e) {                           \
      float& m_e = e ? m1 : m0;                                               \
      float& ls_e = e ? ls1 : ls0;                                            \
      float mx = sa[e][0][0];                                                 \
      _Pragma("unroll") for (int sf = 0; sf < 4; ++sf)                        \
        _Pragma("unroll") for (int r = 0; r < 4; ++r)                         \
          mx = fmaxf(mx, sa[e][sf][r]);                                       \
      mx = fmaxf(mx, __shfl_xor(mx, 16));                                     \
      mx = fmaxf(mx, __shfl_xor(mx, 32));                                     \
      if (__any(mx > m_e + THR_LOG2)) {                                       \
        float mn = fmaxf(m_e, mx);                                            \
        float sc = fexp2(m_e - mn);                                           \
        m_e = mn;                                                             \
        ls_e *= sc;                                                           \
        float scr[4];                                                         \
        _Pragma("unroll") for (int r = 0; r < 4; ++r) scr[r] = __shfl(sc, g * 4 + r); \
        _Pragma("unroll") for (int ff = 0; ff < 8; ++ff)                      \
          _Pragma("unroll") for (int r = 0; r < 4; ++r) O[e][ff][r] *= scr[r]; \
      }                                                                       \
      float p[4][4];                                                          \
      float sum = 0.f;                                                        \
      _Pragma("unroll") for (int sf = 0; sf < 4; ++sf)                        \
        _Pragma("unroll") for (int r = 0; r < 4; ++r) {                       \
          float pv = fexp2(sa[e][sf][r] - m_e);                               \
          p[sf][r] = pv;                                                      \
          sum += pv;                                                          \
        }                                                                     \
      sum += __shfl_xor(sum, 16);                                             \
      sum += __shfl_xor(sum, 32);                                             \
      ls_e += sum;                                                            \
      paf[e][0] = (bf16x8){(__bf16)p[0][0], (__bf16)p[0][1], (__bf16)p[0][2], (__bf16)p[0][3], \
                           (__bf16)p[1][0], (__bf16)p[1][1], (__bf16)p[1][2], (__bf16)p[1][3]}; \
      paf[e][1] = (bf16x8){(__bf16)p[2][0], (__bf16)p[2][1], (__bf16)p[2][2], (__bf16)p[2][3], \
                           (__bf16)p[3][0], (__bf16)p[3][1], (__bf16)p[3][2], (__bf16)p[3][3]}; \
    }                                                                         \
    __builtin_amdgcn_s_setprio(1);                                            \
    bf16x8 vv1[8];                                                            \
    _Pragma("unroll") for (int f = 0; f < 8; ++f)                             \
      vv1[f] = *(const bf16x8*)&smem[(vOff) + kb1 + f * 1024];                \
    _Pragma("unroll") for (int f = 0; f < 8; ++f) {                           \
      O[0][f] = mfma16(paf[0][0], vv0[f], O[0][f]);                           \
      O[1][f] = mfma16(paf[1][0], vv0[f], O[1][f]);                           \
    }                                                                         \
    _Pragma("unroll") for (int f = 0; f < 8; ++f) {                           \
      O[0][f] = mfma16(paf[0][1], vv1[f], O[0][f]);                           \
      O[1][f] = mfma16(paf[1][1], vv1[f], O[1][f]);                           \
    }                                                                         \
    __builtin_amdgcn_s_setprio(0);                                            \
  } while (0)

  STAGE(0, 8192, 0);

#pragma unroll 1
  for (int t = 0; t < 32; t += 2) {
    __syncthreads();  // vmcnt(0): buf0 staged; all waves done with buf1
    STAGE(4096, 16384, (t + 1) * 64);
    TILE(0, 8192);
    __syncthreads();  // buf1 staged; all waves done with buf0
    if (t < 30) STAGE(0, 8192, (t + 2) * 64);
    TILE(4096, 16384);
  }

  // epilogue: redistribute 1/ls from c-layout to (g,r)-layout
  float inv0 = 1.f / ls0, inv1 = 1.f / ls1;
  float i0[4], i1[4];
#pragma unroll
  for (int r = 0; r < 4; ++r) {
    i0[r] = __shfl(inv0, g * 4 + r);
    i1[r] = __shfl(inv1, g * 4 + r);
  }
  float res[8][4];
  float ss[4] = {0.f, 0.f, 0.f, 0.f};
#pragma unroll
  for (int f = 0; f < 8; ++f)
#pragma unroll
    for (int r = 0; r < 4; ++r) {
      float vv = O[0][f][r] * i0[r] - lambda_full * (O[1][f][r] * i1[r]);
      res[f][r] = vv;
      ss[r] += vv * vv;
    }
#pragma unroll
  for (int off = 1; off < 16; off <<= 1)
#pragma unroll
    for (int r = 0; r < 4; ++r) ss[r] += __shfl_xor(ss[r], off);
  float rms[4];
#pragma unroll
  for (int r = 0; r < 4; ++r)
    rms[r] = rsqrtf(ss[r] * (1.0f / 128.0f) + 1e-5f) * ONE_MINUS_LI;
  float w[8];
#pragma unroll
  for (int f = 0; f < 8; ++f) w[f] = subln[f * 16 + c];
#pragma unroll
  for (int f = 0; f < 8; ++f)
#pragma unroll
    for (int r = 0; r < 4; ++r)
      AO[(size_t)(t0 + g * 4 + r) * 2048 + h * 128 + f * 16 + c] = f2b(res[f][r] * rms[r] * w[f]);
}

// ------------------------------------------------------------------------------
extern "C" void kernel_launch(void* const* d_in, const int* in_sizes, int n_in,
                              void* d_out, int out_size, void* d_ws, size_t ws_size,
                              hipStream_t stream) {
  const float* q     = (const float*)d_in[0];
  const float* k     = (const float*)d_in[1];
  const float* v     = (const float*)d_in[2];
  const float* Wq    = (const float*)d_in[3];
  const float* Wk    = (const float*)d_in[4];
  const float* Wv    = (const float*)d_in[5];
  const float* Wout  = (const float*)d_in[6];
  const float* lq1   = (const float*)d_in[7];
  const float* lk1   = (const float*)d_in[8];
  const float* lq2   = (const float*)d_in[9];
  const float* lk2   = (const float*)d_in[10];
  const float* subln = (const float*)d_in[11];
  float* out = (float*)d_out;

  char* ws = (char*)d_ws;
  size_t off = 0;
  auto alloc = [&](size_t bytes) -> void* {
    void* p = ws + off;
    off += (bytes + 255) & ~(size_t)255;
    return p;
  };
  u16* qb  = (u16*)alloc(2048ull * 2048 * 2);
  u16* kb  = (u16*)alloc(2048ull * 2048 * 2);
  u16* vb  = (u16*)alloc(2048ull * 2048 * 2);
  u16* WqT = (u16*)alloc(2048ull * 2048 * 2);
  u16* WkT = (u16*)alloc(1024ull * 2048 * 2);
  u16* WvT = (u16*)alloc(1024ull * 2048 * 2);
  u16* WoT = (u16*)alloc(2048ull * 2048 * 2);
  f32x2* tbl = (f32x2*)alloc(2048ull * 32 * 8);
  u16* Qh  = (u16*)alloc(32ull * 2048 * 64 * 2);
  u16* Kh  = (u16*)alloc(16ull * 2048 * 64 * 2);
  u16* Vt  = (u16*)alloc(1024ull * 2048 * 2);
  u16* AO  = (u16*)alloc(2048ull * 2048 * 2);

  // 1. cast inputs to bf16 + build rope cos/sin table (one launch)
  cast3_kernel<<<6400, 256, 0, stream>>>(q, k, v, qb, kb, vb, tbl);
  // 2. transpose+cast all weights -> [N][K] bf16 (one launch)
  wtrans_kernel<<<dim3(64, 64, 4), 256, 0, stream>>>(Wq, WqT, Wk, WkT, Wv, WvT, Wout, WoT);
  // 3. projections + fused RoPE (Q,K) + fused permuted V-transpose (one launch)
  gemm_qkv_kernel<<<512, 256, 0, stream>>>(qb, WqT, Qh, kb, WkT, Kh, vb, WvT, Vt, tbl);
  // 4. differential flash attention -> AO bf16 [2048][2048]
  attn_kernel<<<256, 512, 0, stream>>>(Qh, Kh, Vt, AO, lq1, lk1, lq2, lk2, subln);
  // 5. output projection -> f32 d_out
  gemm_one_kernel<<<256, 256, 0, stream>>>(AO, WoT, out);
}